// Round 1
// baseline (3011.745 us; speedup 1.0000x reference)
//
#include <hip/hip_runtime.h>

#define NNODES 50000
#define NEDGES 800000
#define DIN    256
#define DOUT   512
#define MP     50048          // ceil(NNODES/128)*128
#define BN_EPS 1e-5f

typedef __attribute__((ext_vector_type(8))) __bf16 bf16x8;
typedef __attribute__((ext_vector_type(4))) float  floatx4;

__device__ __forceinline__ ushort f2bf(float f) {
    union { float f; uint u; } v; v.f = f;
    uint u = v.u;
    return (ushort)((u + 0x7FFFu + ((u >> 16) & 1u)) >> 16);   // RNE
}
__device__ __forceinline__ float bf2f(ushort b) {
    union { uint u; float f; } v; v.u = ((uint)b) << 16;
    return v.f;
}

// ---------------- h0 = x (seed for scatter-add) ----------------
__global__ void k_copy_x(const float4* __restrict__ x, float4* __restrict__ h0) {
    size_t i = (size_t)blockIdx.x * 256 + threadIdx.x;
    h0[i] = x[i];
}

// ---------------- scatter: h0[row] += w * x[col] ----------------
__global__ void k_scatter(const float* __restrict__ x, const int* __restrict__ ei,
                          const float* __restrict__ ew, float* __restrict__ h0) {
    int t = threadIdx.x;
    int e = blockIdx.x * 4 + (t >> 6);          // 4 edges / 256-thread block
    int r = ei[e];
    int c = ei[NEDGES + e];
    float w = ew[e];
    int c4 = (t & 63) * 4;
    float4 v = *(const float4*)(x + (size_t)c * DIN + c4);
    float* dst = h0 + (size_t)r * DIN + c4;
    atomicAdd(dst + 0, w * v.x);
    atomicAdd(dst + 1, w * v.y);
    atomicAdd(dst + 2, w * v.z);
    atomicAdd(dst + 3, w * v.w);
}

// ---------------- f32 -> bf16, pad rows [NNODES, MP) with zeros ----------------
__global__ void k_cvt_h0(const float* __restrict__ h0, ushort* __restrict__ h0b) {
    int idx = blockIdx.x * 256 + threadIdx.x;   // MP*64 threads, 4 elems each
    int row = idx >> 6;
    int c4  = (idx & 63) * 4;
    float4 v = make_float4(0.f, 0.f, 0.f, 0.f);
    if (row < NNODES) v = *(const float4*)(h0 + (size_t)row * DIN + c4);
    ushort4 o;
    o.x = f2bf(v.x); o.y = f2bf(v.y); o.z = f2bf(v.z); o.w = f2bf(v.w);
    *(ushort4*)(h0b + (size_t)row * DIN + c4) = o;
}

// ---------------- W (K x Nc) f32 -> WT (Nc x K) bf16 ----------------
__global__ void k_transpose(const float* __restrict__ W, ushort* __restrict__ WT,
                            int K, int Nc) {
    __shared__ float tile[32][33];
    int t  = threadIdx.x;
    int lx = t & 31, ly = t >> 5;               // ly 0..7
    int bx = blockIdx.x;                        // along Nc
    int by = blockIdx.y;                        // along K
    #pragma unroll
    for (int p = 0; p < 4; ++p)
        tile[ly + p * 8][lx] = W[(size_t)(by * 32 + ly + p * 8) * Nc + bx * 32 + lx];
    __syncthreads();
    #pragma unroll
    for (int p = 0; p < 4; ++p)
        WT[(size_t)(bx * 32 + ly + p * 8) * K + by * 32 + lx] = f2bf(tile[lx][ly + p * 8]);
}

// ---------------- bf16 MFMA GEMM: C = A @ BT^T + bias ----------------
// A: MP x KDIM bf16, BT: DOUT x KDIM bf16 (row-major N x K)
// OUT_BF16: write bf16 (all MP rows)   else: write f32, guard row < NNODES
template<int KDIM, bool OUT_BF16>
__global__ __launch_bounds__(256) void k_gemm(const ushort* __restrict__ A,
                                              const ushort* __restrict__ BT,
                                              const float* __restrict__ bias,
                                              void* __restrict__ out) {
    constexpr int LDSK = 64 + 8;                // +8 bf16 pad kills bank conflicts
    __shared__ ushort As[128][LDSK];
    __shared__ ushort Bs[128][LDSK];

    int t    = threadIdx.x;
    int bm   = blockIdx.x >> 2;
    int bn   = blockIdx.x & 3;
    int lane = t & 63;
    int w    = t >> 6;
    int wr   = w >> 1, wc = w & 1;              // 2x2 waves -> 64x64 each
    int l15  = lane & 15, l4 = lane >> 4;

    floatx4 acc[4][4] = {};

    int arow = t >> 3;                          // 0..31
    int acol = (t & 7) * 8;                     // 0..56
    const size_t abase = (size_t)(bm * 128) * KDIM;
    const size_t bbase = (size_t)(bn * 128) * KDIM;

    for (int k0 = 0; k0 < KDIM; k0 += 64) {
        #pragma unroll
        for (int p = 0; p < 4; ++p) {
            int row = p * 32 + arow;
            uint4 va = *(const uint4*)(A  + abase + (size_t)row * KDIM + k0 + acol);
            *(uint4*)&As[row][acol] = va;
            uint4 vb = *(const uint4*)(BT + bbase + (size_t)row * KDIM + k0 + acol);
            *(uint4*)&Bs[row][acol] = vb;
        }
        __syncthreads();
        #pragma unroll
        for (int ks = 0; ks < 2; ++ks) {
            bf16x8 af[4], bfr[4];
            #pragma unroll
            for (int m = 0; m < 4; ++m)
                af[m] = *(const bf16x8*)&As[wr * 64 + m * 16 + l15][ks * 32 + l4 * 8];
            #pragma unroll
            for (int n = 0; n < 4; ++n)
                bfr[n] = *(const bf16x8*)&Bs[wc * 64 + n * 16 + l15][ks * 32 + l4 * 8];
            #pragma unroll
            for (int m = 0; m < 4; ++m)
                #pragma unroll
                for (int n = 0; n < 4; ++n)
                    acc[m][n] = __builtin_amdgcn_mfma_f32_16x16x32_bf16(af[m], bfr[n], acc[m][n], 0, 0, 0);
        }
        __syncthreads();
    }

    // epilogue: D row = (lane>>4)*4 + reg, col = lane&15   [m89-verified layout]
    #pragma unroll
    for (int n = 0; n < 4; ++n) {
        int col = bn * 128 + wc * 64 + n * 16 + l15;
        float bv = bias[col];
        #pragma unroll
        for (int m = 0; m < 4; ++m) {
            int rbase = bm * 128 + wr * 64 + m * 16 + l4 * 4;
            #pragma unroll
            for (int i = 0; i < 4; ++i) {
                int grow = rbase + i;
                float vv = acc[m][n][i] + bv;
                if (OUT_BF16) {
                    ((ushort*)out)[(size_t)grow * DOUT + col] = f2bf(vv);
                } else {
                    if (grow < NNODES)
                        ((float*)out)[(size_t)grow * DOUT + col] = vv;
                }
            }
        }
    }
}

// ---------------- BN stats ----------------
__global__ void k_zero_stats(float* s) {
    int i = blockIdx.x * 256 + threadIdx.x;
    if (i < 1024) s[i] = 0.f;
}

__global__ void k_stats(const ushort* __restrict__ h1b,
                        float* __restrict__ sum, float* __restrict__ sumsq) {
    int t  = threadIdx.x;
    int c0 = t * 2;
    int r0 = blockIdx.x * 256;
    int rend = min(r0 + 256, NNODES);
    float s0 = 0, s1 = 0, q0 = 0, q1 = 0;
    for (int r = r0; r < rend; ++r) {
        uint v = *(const uint*)(h1b + (size_t)r * DOUT + c0);
        float a = bf2f((ushort)(v & 0xffff));
        float b = bf2f((ushort)(v >> 16));
        s0 += a; q0 += a * a;
        s1 += b; q1 += b * b;
    }
    atomicAdd(&sum[c0],     s0);
    atomicAdd(&sum[c0 + 1], s1);
    atomicAdd(&sumsq[c0],     q0);
    atomicAdd(&sumsq[c0 + 1], q1);
}

__global__ void k_bn_finalize(const float* __restrict__ sum, const float* __restrict__ sumsq,
                              const float* __restrict__ gamma, const float* __restrict__ beta,
                              float* __restrict__ scale, float* __restrict__ shift) {
    int c = threadIdx.x;                        // 512 threads
    float mean = sum[c] * (1.0f / NNODES);
    float var  = sumsq[c] * (1.0f / NNODES) - mean * mean;
    float sc   = gamma[c] * rsqrtf(var + BN_EPS);
    scale[c] = sc;
    shift[c] = beta[c] - mean * sc;
}

// ---------------- in-place BN apply + ReLU on bf16 h1 ----------------
__global__ void k_bn_apply(ushort* __restrict__ h1b, const float* __restrict__ scale,
                           const float* __restrict__ shift) {
    size_t idx  = (size_t)blockIdx.x * 256 + threadIdx.x;   // MP*64 threads, 8 elems each
    size_t base = idx * 8;
    int c0 = (int)(base & (DOUT - 1));
    uint4 v = *(uint4*)(h1b + base);
    uint vv[4] = {v.x, v.y, v.z, v.w};
    uint o[4];
    #pragma unroll
    for (int j = 0; j < 4; ++j) {
        int c = c0 + j * 2;
        float a = bf2f((ushort)(vv[j] & 0xffff));
        float b = bf2f((ushort)(vv[j] >> 16));
        a = fmaxf(a * scale[c]     + shift[c],     0.f);
        b = fmaxf(b * scale[c + 1] + shift[c + 1], 0.f);
        o[j] = (uint)f2bf(a) | ((uint)f2bf(b) << 16);
    }
    uint4 ov; ov.x = o[0]; ov.y = o[1]; ov.z = o[2]; ov.w = o[3];
    *(uint4*)(h1b + base) = ov;
}

extern "C" void kernel_launch(void* const* d_in, const int* in_sizes, int n_in,
                              void* d_out, int out_size, void* d_ws, size_t ws_size,
                              hipStream_t stream) {
    const float* x     = (const float*)d_in[0];
    const int*   ei    = (const int*)  d_in[1];
    const float* ew    = (const float*)d_in[2];
    const float* W1    = (const float*)d_in[3];
    const float* b1    = (const float*)d_in[4];
    const float* gamma = (const float*)d_in[5];
    const float* beta  = (const float*)d_in[6];
    const float* W2    = (const float*)d_in[7];
    const float* b2    = (const float*)d_in[8];

    // workspace layout (~52 MB)
    char* ws = (char*)d_ws;
    ushort* h1b = (ushort*)ws;                       size_t off = (size_t)MP * DOUT * 2;
    ushort* W1T = (ushort*)(ws + off);               off += (size_t)DOUT * DIN * 2;
    ushort* W2T = (ushort*)(ws + off);               off += (size_t)DOUT * DOUT * 2;
    float* colsum   = (float*)(ws + off);            off += 512 * 4;
    float* colsumsq = (float*)(ws + off);            off += 512 * 4;
    float* scale    = (float*)(ws + off);            off += 512 * 4;
    float* shift    = (float*)(ws + off);            off += 512 * 4;

    // d_out double-duty: h0 (f32) + h0b (bf16) live before GEMM2 overwrites
    float*  h0   = (float*)d_out;                                  // NNODES*DIN f32
    ushort* h0b  = (ushort*)((char*)d_out + (size_t)NNODES * DIN * 4); // MP*DIN bf16
    float*  outp = (float*)d_out;

    k_zero_stats<<<4, 256, 0, stream>>>(colsum);     // colsum+colsumsq contiguous
    k_copy_x<<<(NNODES * DIN / 4) / 256, 256, 0, stream>>>((const float4*)x, (float4*)h0);
    k_transpose<<<dim3(DOUT / 32, DIN / 32),  256, 0, stream>>>(W1, W1T, DIN,  DOUT);
    k_transpose<<<dim3(DOUT / 32, DOUT / 32), 256, 0, stream>>>(W2, W2T, DOUT, DOUT);
    k_scatter<<<NEDGES / 4, 256, 0, stream>>>(x, ei, ew, h0);
    k_cvt_h0<<<MP / 4, 256, 0, stream>>>(h0, h0b);
    k_gemm<DIN, true><<<(MP / 128) * 4, 256, 0, stream>>>(h0b, W1T, b1, (void*)h1b);
    k_stats<<<196, 256, 0, stream>>>(h1b, colsum, colsumsq);
    k_bn_finalize<<<1, 512, 0, stream>>>(colsum, colsumsq, gamma, beta, scale, shift);
    k_bn_apply<<<MP / 4, 256, 0, stream>>>(h1b, scale, shift);
    k_gemm<DOUT, false><<<(MP / 128) * 4, 256, 0, stream>>>(h1b, W2T, b2, (void*)outp);
}

// Round 3
// 544.112 us; speedup vs baseline: 5.5352x; 5.5352x over previous
//
#include <hip/hip_runtime.h>

#define NNODES 50000
#define NEDGES 800000
#define DIN    256
#define DOUT   512
#define MP     50048          // ceil(NNODES/128)*128
#define BN_EPS 1e-5f
#define NBLK   196            // ceil(NNODES/256) scan blocks

typedef __attribute__((ext_vector_type(8))) __bf16 bf16x8;
typedef __attribute__((ext_vector_type(4))) float  floatx4;

__device__ __forceinline__ ushort f2bf(float f) {
    union { float f; uint u; } v; v.f = f;
    uint u = v.u;
    return (ushort)((u + 0x7FFFu + ((u >> 16) & 1u)) >> 16);   // RNE
}
__device__ __forceinline__ float bf2f(ushort b) {
    union { uint u; float f; } v; v.u = ((uint)b) << 16;
    return v.f;
}

// ---------------- CSR build ----------------
__global__ void k_zero_int(int* __restrict__ p, int n) {
    int i = blockIdx.x * 256 + threadIdx.x;
    if (i < n) p[i] = 0;
}

__global__ void k_count(const int* __restrict__ ei, int* __restrict__ deg) {
    int e = blockIdx.x * 256 + threadIdx.x;
    atomicAdd(&deg[ei[e]], 1);
}

// per-block exclusive scan of deg -> rowstart (block-local), block sums -> bsum
__global__ void k_scan_block(const int* __restrict__ deg, int* __restrict__ rowstart,
                             int* __restrict__ bsum) {
    __shared__ int s[256];
    int t = threadIdx.x;
    int i = blockIdx.x * 256 + t;
    int v = (i < NNODES) ? deg[i] : 0;
    s[t] = v; __syncthreads();
    #pragma unroll
    for (int d = 1; d < 256; d <<= 1) {
        int add = (t >= d) ? s[t - d] : 0;
        __syncthreads();
        s[t] += add;
        __syncthreads();
    }
    if (i < MP) rowstart[i] = s[t] - v;          // exclusive, block-local
    if (t == 255) bsum[blockIdx.x] = s[255];
}

// exclusive scan of the block sums -> bofs (single block)
__global__ void k_scan_bsum(const int* __restrict__ bsum, int* __restrict__ bofs) {
    __shared__ int s[256];
    int t = threadIdx.x;
    int v = (t < NBLK) ? bsum[t] : 0;
    s[t] = v; __syncthreads();
    #pragma unroll
    for (int d = 1; d < 256; d <<= 1) {
        int add = (t >= d) ? s[t - d] : 0;
        __syncthreads();
        s[t] += add;
        __syncthreads();
    }
    bofs[t] = s[t] - v;
}

// fill buckets: cw[pos] = {col, weight}
__global__ void k_bucket(const int* __restrict__ ei, const float* __restrict__ ew,
                         const int* __restrict__ rowstart, const int* __restrict__ bofs,
                         int* __restrict__ cursor, int2* __restrict__ cw) {
    int e = blockIdx.x * 256 + threadIdx.x;
    int r = ei[e];
    int c = ei[NEDGES + e];
    float w = ew[e];
    int pos = rowstart[r] + bofs[r >> 8] + atomicAdd(&cursor[r], 1);
    cw[pos] = make_int2(c, __float_as_int(w));
}

// ---------------- gather-aggregate: h0b[n] = bf16( x[n] + sum_e w_e * x[col_e] ) ----------------
__global__ __launch_bounds__(256) void k_aggregate(const float* __restrict__ x,
                                                   const int2* __restrict__ cw,
                                                   const int* __restrict__ rowstart,
                                                   const int* __restrict__ bofs,
                                                   const int* __restrict__ deg,
                                                   ushort* __restrict__ h0b) {
    int t = threadIdx.x;
    int wv = t >> 6, lane = t & 63;
    int n = blockIdx.x * 4 + wv;                 // one wave per node, grid = MP/4
    if (n >= MP) return;
    ushort* dst = h0b + (size_t)n * DIN + lane * 4;
    if (n >= NNODES) {                           // zero the pad rows
        *(ushort4*)dst = make_ushort4(0, 0, 0, 0);
        return;
    }
    const float* xr = x + (size_t)n * DIN + lane * 4;
    float4 acc = *(const float4*)xr;
    int start = rowstart[n] + bofs[n >> 8];
    int end   = start + deg[n];
    for (int j = start; j < end; ++j) {
        int2 cv = cw[j];                         // wave-uniform 8B load (broadcast)
        float w = __int_as_float(cv.y);
        float4 v = *(const float4*)(x + (size_t)cv.x * DIN + lane * 4);
        acc.x += w * v.x; acc.y += w * v.y; acc.z += w * v.z; acc.w += w * v.w;
    }
    ushort4 o;
    o.x = f2bf(acc.x); o.y = f2bf(acc.y); o.z = f2bf(acc.z); o.w = f2bf(acc.w);
    *(ushort4*)dst = o;
}

// ---------------- W (K x Nc) f32 -> WT (Nc x K) bf16 ----------------
__global__ void k_transpose(const float* __restrict__ W, ushort* __restrict__ WT,
                            int K, int Nc) {
    __shared__ float tile[32][33];
    int t  = threadIdx.x;
    int lx = t & 31, ly = t >> 5;                // ly 0..7
    int bx = blockIdx.x;                         // along Nc
    int by = blockIdx.y;                         // along K
    #pragma unroll
    for (int p = 0; p < 4; ++p)
        tile[ly + p * 8][lx] = W[(size_t)(by * 32 + ly + p * 8) * Nc + bx * 32 + lx];
    __syncthreads();
    #pragma unroll
    for (int p = 0; p < 4; ++p)
        WT[(size_t)(bx * 32 + ly + p * 8) * K + by * 32 + lx] = f2bf(tile[lx][ly + p * 8]);
}

// ---------------- bf16 MFMA GEMM: C = A @ BT^T + bias ----------------
template<int KDIM, bool OUT_BF16>
__global__ __launch_bounds__(256) void k_gemm(const ushort* __restrict__ A,
                                              const ushort* __restrict__ BT,
                                              const float* __restrict__ bias,
                                              void* __restrict__ out) {
    constexpr int LDSK = 64 + 8;                 // +8 bf16 pad kills bank conflicts
    __shared__ ushort As[128][LDSK];
    __shared__ ushort Bs[128][LDSK];

    int t    = threadIdx.x;
    int bm   = blockIdx.x >> 2;
    int bn   = blockIdx.x & 3;
    int lane = t & 63;
    int w    = t >> 6;
    int wr   = w >> 1, wc = w & 1;               // 2x2 waves -> 64x64 each
    int l15  = lane & 15, l4 = lane >> 4;

    floatx4 acc[4][4] = {};

    int arow = t >> 3;                           // 0..31
    int acol = (t & 7) * 8;                      // 0..56
    const size_t abase = (size_t)(bm * 128) * KDIM;
    const size_t bbase = (size_t)(bn * 128) * KDIM;

    for (int k0 = 0; k0 < KDIM; k0 += 64) {
        #pragma unroll
        for (int p = 0; p < 4; ++p) {
            int row = p * 32 + arow;
            uint4 va = *(const uint4*)(A  + abase + (size_t)row * KDIM + k0 + acol);
            *(uint4*)&As[row][acol] = va;
            uint4 vb = *(const uint4*)(BT + bbase + (size_t)row * KDIM + k0 + acol);
            *(uint4*)&Bs[row][acol] = vb;
        }
        __syncthreads();
        #pragma unroll
        for (int ks = 0; ks < 2; ++ks) {
            bf16x8 af[4], bfr[4];
            #pragma unroll
            for (int m = 0; m < 4; ++m)
                af[m] = *(const bf16x8*)&As[wr * 64 + m * 16 + l15][ks * 32 + l4 * 8];
            #pragma unroll
            for (int n = 0; n < 4; ++n)
                bfr[n] = *(const bf16x8*)&Bs[wc * 64 + n * 16 + l15][ks * 32 + l4 * 8];
            #pragma unroll
            for (int m = 0; m < 4; ++m)
                #pragma unroll
                for (int n = 0; n < 4; ++n)
                    acc[m][n] = __builtin_amdgcn_mfma_f32_16x16x32_bf16(af[m], bfr[n], acc[m][n], 0, 0, 0);
        }
        __syncthreads();
    }

    #pragma unroll
    for (int n = 0; n < 4; ++n) {
        int col = bn * 128 + wc * 64 + n * 16 + l15;
        float bv = bias[col];
        #pragma unroll
        for (int m = 0; m < 4; ++m) {
            int rbase = bm * 128 + wr * 64 + m * 16 + l4 * 4;
            #pragma unroll
            for (int i = 0; i < 4; ++i) {
                int grow = rbase + i;
                float vv = acc[m][n][i] + bv;
                if (OUT_BF16) {
                    ((ushort*)out)[(size_t)grow * DOUT + col] = f2bf(vv);
                } else {
                    if (grow < NNODES)
                        ((float*)out)[(size_t)grow * DOUT + col] = vv;
                }
            }
        }
    }
}

// ---------------- BN stats ----------------
__global__ void k_zero_stats(float* s) {
    int i = blockIdx.x * 256 + threadIdx.x;
    if (i < 1024) s[i] = 0.f;
}

__global__ void k_stats(const ushort* __restrict__ h1b,
                        float* __restrict__ sum, float* __restrict__ sumsq) {
    int t  = threadIdx.x;
    int c0 = t * 2;
    int r0 = blockIdx.x * 256;
    int rend = min(r0 + 256, NNODES);
    float s0 = 0, s1 = 0, q0 = 0, q1 = 0;
    for (int r = r0; r < rend; ++r) {
        uint v = *(const uint*)(h1b + (size_t)r * DOUT + c0);
        float a = bf2f((ushort)(v & 0xffff));
        float b = bf2f((ushort)(v >> 16));
        s0 += a; q0 += a * a;
        s1 += b; q1 += b * b;
    }
    atomicAdd(&sum[c0],     s0);
    atomicAdd(&sum[c0 + 1], s1);
    atomicAdd(&sumsq[c0],     q0);
    atomicAdd(&sumsq[c0 + 1], q1);
}

__global__ void k_bn_finalize(const float* __restrict__ sum, const float* __restrict__ sumsq,
                              const float* __restrict__ gamma, const float* __restrict__ beta,
                              float* __restrict__ scale, float* __restrict__ shift) {
    int c = threadIdx.x;                         // 512 threads
    float mean = sum[c] * (1.0f / NNODES);
    float var  = sumsq[c] * (1.0f / NNODES) - mean * mean;
    float sc   = gamma[c] * rsqrtf(var + BN_EPS);
    scale[c] = sc;
    shift[c] = beta[c] - mean * sc;
}

// ---------------- in-place BN apply + ReLU on bf16 h1 ----------------
__global__ void k_bn_apply(ushort* __restrict__ h1b, const float* __restrict__ scale,
                           const float* __restrict__ shift) {
    size_t idx  = (size_t)blockIdx.x * 256 + threadIdx.x;   // MP*64 threads, 8 elems each
    size_t base = idx * 8;
    int c0 = (int)(base & (DOUT - 1));
    uint4 v = *(uint4*)(h1b + base);
    uint vv[4] = {v.x, v.y, v.z, v.w};
    uint o[4];
    #pragma unroll
    for (int j = 0; j < 4; ++j) {
        int c = c0 + j * 2;
        float a = bf2f((ushort)(vv[j] & 0xffff));
        float b = bf2f((ushort)(vv[j] >> 16));
        a = fmaxf(a * scale[c]     + shift[c],     0.f);
        b = fmaxf(b * scale[c + 1] + shift[c + 1], 0.f);
        o[j] = (uint)f2bf(a) | ((uint)f2bf(b) << 16);
    }
    uint4 ov; ov.x = o[0]; ov.y = o[1]; ov.z = o[2]; ov.w = o[3];
    *(uint4*)(h1b + base) = ov;
}

extern "C" void kernel_launch(void* const* d_in, const int* in_sizes, int n_in,
                              void* d_out, int out_size, void* d_ws, size_t ws_size,
                              hipStream_t stream) {
    const float* x     = (const float*)d_in[0];
    const int*   ei    = (const int*)  d_in[1];
    const float* ew    = (const float*)d_in[2];
    const float* W1    = (const float*)d_in[3];
    const float* b1    = (const float*)d_in[4];
    const float* gamma = (const float*)d_in[5];
    const float* beta  = (const float*)d_in[6];
    const float* W2    = (const float*)d_in[7];
    const float* b2    = (const float*)d_in[8];

    // ---- ws layout (~52 MB, unchanged from passing round) ----
    char* ws = (char*)d_ws;
    ushort* h1b = (ushort*)ws;                       size_t off = (size_t)MP * DOUT * 2;
    ushort* W1T = (ushort*)(ws + off);               off += (size_t)DOUT * DIN * 2;
    ushort* W2T = (ushort*)(ws + off);               off += (size_t)DOUT * DOUT * 2;
    float* colsum   = (float*)(ws + off);            off += 512 * 4;
    float* colsumsq = (float*)(ws + off);            off += 512 * 4;
    float* scale    = (float*)(ws + off);            off += 512 * 4;
    float* shift    = (float*)(ws + off);            off += 512 * 4;

    // ---- d_out double-duty: h0b + CSR scratch, all dead before GEMM2 writes ----
    char* ob = (char*)d_out;
    ushort* h0b     = (ushort*)ob;                   size_t ooff = (size_t)MP * DIN * 2;
    int2*   cw      = (int2*)(ob + ooff);            ooff += (size_t)NEDGES * 8;
    int*    deg     = (int*)(ob + ooff);             ooff += (size_t)MP * 4;
    int*    rowstart= (int*)(ob + ooff);             ooff += (size_t)MP * 4;
    int*    cursor  = (int*)(ob + ooff);             ooff += (size_t)MP * 4;
    int*    bsum    = (int*)(ob + ooff);             ooff += 256 * 4;
    int*    bofs    = (int*)(ob + ooff);             ooff += 256 * 4;
    float*  outp    = (float*)d_out;

    // CSR build
    k_zero_int<<<(2 * MP + 255) / 256, 256, 0, stream>>>(deg, 2 * MP);   // deg & cursor region zeroed
    k_zero_int<<<(MP + 255) / 256, 256, 0, stream>>>(cursor, MP);
    k_count<<<NEDGES / 256, 256, 0, stream>>>(ei, deg);
    k_scan_block<<<NBLK, 256, 0, stream>>>(deg, rowstart, bsum);
    k_scan_bsum<<<1, 256, 0, stream>>>(bsum, bofs);
    k_bucket<<<NEDGES / 256, 256, 0, stream>>>(ei, ew, rowstart, bofs, cursor, cw);

    // weights + stats init (independent, can overlap CSR chain in HW queue)
    k_zero_stats<<<4, 256, 0, stream>>>(colsum);     // colsum+colsumsq contiguous
    k_transpose<<<dim3(DOUT / 32, DIN / 32),  256, 0, stream>>>(W1, W1T, DIN,  DOUT);
    k_transpose<<<dim3(DOUT / 32, DOUT / 32), 256, 0, stream>>>(W2, W2T, DOUT, DOUT);

    // aggregate (gather, no atomics) -> bf16
    k_aggregate<<<MP / 4, 256, 0, stream>>>(x, cw, rowstart, bofs, deg, h0b);

    // MLP
    k_gemm<DIN, true><<<(MP / 128) * 4, 256, 0, stream>>>(h0b, W1T, b1, (void*)h1b);
    k_stats<<<NBLK, 256, 0, stream>>>(h1b, colsum, colsumsq);
    k_bn_finalize<<<1, 512, 0, stream>>>(colsum, colsumsq, gamma, beta, scale, shift);
    k_bn_apply<<<MP / 4, 256, 0, stream>>>(h1b, scale, shift);
    k_gemm<DOUT, false><<<(MP / 128) * 4, 256, 0, stream>>>(h1b, W2T, b2, (void*)outp);
}

// Round 4
// 460.455 us; speedup vs baseline: 6.5408x; 1.1817x over previous
//
#include <hip/hip_runtime.h>

#define NNODES 50000
#define NEDGES 800000
#define DIN    256
#define DOUT   512
#define MP     50048          // ceil(NNODES/128)*128
#define BN_EPS 1e-5f
#define NBLK   196            // ceil(NNODES/256) scan blocks

typedef __attribute__((ext_vector_type(8))) __bf16 bf16x8;
typedef __attribute__((ext_vector_type(4))) float  floatx4;

__device__ __forceinline__ ushort f2bf(float f) {
    union { float f; uint u; } v; v.f = f;
    uint u = v.u;
    return (ushort)((u + 0x7FFFu + ((u >> 16) & 1u)) >> 16);   // RNE
}
__device__ __forceinline__ float bf2f(ushort b) {
    union { uint u; float f; } v; v.u = ((uint)b) << 16;
    return v.f;
}
// BN+ReLU on a packed pair of bf16 while staging
__device__ __forceinline__ uint bnpack(uint u, float s0, float s1, float h0, float h1) {
    float a = bf2f((ushort)(u & 0xffff)) * s0 + h0;
    float b = bf2f((ushort)(u >> 16))    * s1 + h1;
    a = fmaxf(a, 0.f); b = fmaxf(b, 0.f);
    return (uint)f2bf(a) | ((uint)f2bf(b) << 16);
}

// ---------------- init: zero deg+cursor (2*MP ints) and colsum/colsumsq (1024 f32) ----------------
__global__ void k_zero(int* __restrict__ a, float* __restrict__ b) {
    int i = blockIdx.x * 256 + threadIdx.x;
    if (i < 2 * MP) a[i] = 0;
    if (i < 1024)   b[i] = 0.f;
}

__global__ void k_count(const int* __restrict__ ei, int* __restrict__ deg) {
    int e = blockIdx.x * 256 + threadIdx.x;
    atomicAdd(&deg[ei[e]], 1);
}

// per-block exclusive scan of deg -> rowstart (block-local), block sums -> bsum
__global__ void k_scan_block(const int* __restrict__ deg, int* __restrict__ rowstart,
                             int* __restrict__ bsum) {
    __shared__ int s[256];
    int t = threadIdx.x;
    int i = blockIdx.x * 256 + t;
    int v = (i < NNODES) ? deg[i] : 0;
    s[t] = v; __syncthreads();
    #pragma unroll
    for (int d = 1; d < 256; d <<= 1) {
        int add = (t >= d) ? s[t - d] : 0;
        __syncthreads();
        s[t] += add;
        __syncthreads();
    }
    if (i < MP) rowstart[i] = s[t] - v;          // exclusive, block-local
    if (t == 255) bsum[blockIdx.x] = s[255];
}

// exclusive scan of the block sums -> bofs (single block)
__global__ void k_scan_bsum(const int* __restrict__ bsum, int* __restrict__ bofs) {
    __shared__ int s[256];
    int t = threadIdx.x;
    int v = (t < NBLK) ? bsum[t] : 0;
    s[t] = v; __syncthreads();
    #pragma unroll
    for (int d = 1; d < 256; d <<= 1) {
        int add = (t >= d) ? s[t - d] : 0;
        __syncthreads();
        s[t] += add;
        __syncthreads();
    }
    bofs[t] = s[t] - v;
}

// fill buckets: cw[pos] = {col, weight}
__global__ void k_bucket(const int* __restrict__ ei, const float* __restrict__ ew,
                         const int* __restrict__ rowstart, const int* __restrict__ bofs,
                         int* __restrict__ cursor, int2* __restrict__ cw) {
    int e = blockIdx.x * 256 + threadIdx.x;
    int r = ei[e];
    int c = ei[NEDGES + e];
    float w = ew[e];
    int pos = rowstart[r] + bofs[r >> 8] + atomicAdd(&cursor[r], 1);
    cw[pos] = make_int2(c, __float_as_int(w));
}

// ---------------- gather-aggregate: h0b[n] = bf16( x[n] + sum_e w_e * x[col_e] ) ----------------
// one wave per node; 4x unrolled so 4 row-gathers are in flight per wave
__global__ __launch_bounds__(256) void k_aggregate(const float* __restrict__ x,
                                                   const int2* __restrict__ cw,
                                                   const int* __restrict__ rowstart,
                                                   const int* __restrict__ bofs,
                                                   const int* __restrict__ deg,
                                                   ushort* __restrict__ h0b) {
    int t = threadIdx.x;
    int wv = t >> 6, lane = t & 63;
    int n = blockIdx.x * 4 + wv;
    if (n >= MP) return;
    ushort* dst = h0b + (size_t)n * DIN + lane * 4;
    if (n >= NNODES) {                           // zero the pad rows
        *(ushort4*)dst = make_ushort4(0, 0, 0, 0);
        return;
    }
    const float* xl = x + lane * 4;
    float4 acc = *(const float4*)(xl + (size_t)n * DIN);
    int start = rowstart[n] + bofs[n >> 8];
    int end   = start + deg[n];
    int j = start;
    for (; j + 3 < end; j += 4) {
        int2 e0 = cw[j], e1 = cw[j + 1], e2 = cw[j + 2], e3 = cw[j + 3];
        float4 v0 = *(const float4*)(xl + (size_t)e0.x * DIN);
        float4 v1 = *(const float4*)(xl + (size_t)e1.x * DIN);
        float4 v2 = *(const float4*)(xl + (size_t)e2.x * DIN);
        float4 v3 = *(const float4*)(xl + (size_t)e3.x * DIN);
        float w0 = __int_as_float(e0.y), w1 = __int_as_float(e1.y);
        float w2 = __int_as_float(e2.y), w3 = __int_as_float(e3.y);
        acc.x += w0 * v0.x; acc.y += w0 * v0.y; acc.z += w0 * v0.z; acc.w += w0 * v0.w;
        acc.x += w1 * v1.x; acc.y += w1 * v1.y; acc.z += w1 * v1.z; acc.w += w1 * v1.w;
        acc.x += w2 * v2.x; acc.y += w2 * v2.y; acc.z += w2 * v2.z; acc.w += w2 * v2.w;
        acc.x += w3 * v3.x; acc.y += w3 * v3.y; acc.z += w3 * v3.z; acc.w += w3 * v3.w;
    }
    for (; j < end; ++j) {
        int2 cv = cw[j];
        float w = __int_as_float(cv.y);
        float4 v = *(const float4*)(xl + (size_t)cv.x * DIN);
        acc.x += w * v.x; acc.y += w * v.y; acc.z += w * v.z; acc.w += w * v.w;
    }
    ushort4 o;
    o.x = f2bf(acc.x); o.y = f2bf(acc.y); o.z = f2bf(acc.z); o.w = f2bf(acc.w);
    *(ushort4*)dst = o;
}

// ---------------- W (K x Nc) f32 -> WT (Nc x K) bf16 ----------------
__global__ void k_transpose(const float* __restrict__ W, ushort* __restrict__ WT,
                            int K, int Nc) {
    __shared__ float tile[32][33];
    int t  = threadIdx.x;
    int lx = t & 31, ly = t >> 5;                // ly 0..7
    int bx = blockIdx.x;                         // along Nc
    int by = blockIdx.y;                         // along K
    #pragma unroll
    for (int p = 0; p < 4; ++p)
        tile[ly + p * 8][lx] = W[(size_t)(by * 32 + ly + p * 8) * Nc + bx * 32 + lx];
    __syncthreads();
    #pragma unroll
    for (int p = 0; p < 4; ++p)
        WT[(size_t)(bx * 32 + ly + p * 8) * K + by * 32 + lx] = f2bf(tile[lx][ly + p * 8]);
}

// ---------------- bf16 MFMA GEMM: C = A @ BT^T + bias ----------------
// MODE 1 (GEMM1): bf16 out (all MP rows) + fused BN-stats column reduction
// MODE 2 (GEMM2): BN(scale,shift)+ReLU applied to A during staging, f32 out, row<NNODES guard
template<int KDIM, int MODE>
__global__ __launch_bounds__(256) void k_gemm(const ushort* __restrict__ A,
                                              const ushort* __restrict__ BT,
                                              const float* __restrict__ bias,
                                              const float* __restrict__ scale,
                                              const float* __restrict__ shift,
                                              float* __restrict__ gsum,
                                              float* __restrict__ gsq,
                                              void* __restrict__ out) {
    constexpr int LDSK = 64 + 8;                 // +8 bf16 pad: 2-way-max bank aliasing on b128 reads
    __shared__ ushort As[128][LDSK];
    __shared__ ushort Bs[128][LDSK];

    int t    = threadIdx.x;
    int bm   = blockIdx.x >> 2;
    int bn   = blockIdx.x & 3;
    int lane = t & 63;
    int w    = t >> 6;
    int wr   = w >> 1, wc = w & 1;               // 2x2 waves -> 64x64 each
    int l15  = lane & 15, l4 = lane >> 4;

    floatx4 acc[4][4] = {};

    int arow = t >> 3;                           // 0..31
    int acol = (t & 7) * 8;                      // 0..56
    const size_t abase = (size_t)(bm * 128) * KDIM;
    const size_t bbase = (size_t)(bn * 128) * KDIM;

    for (int k0 = 0; k0 < KDIM; k0 += 64) {
        float4 sc0, sc1, sh0, sh1;
        if (MODE == 2) {
            sc0 = *(const float4*)(scale + k0 + acol);
            sc1 = *(const float4*)(scale + k0 + acol + 4);
            sh0 = *(const float4*)(shift + k0 + acol);
            sh1 = *(const float4*)(shift + k0 + acol + 4);
        }
        #pragma unroll
        for (int p = 0; p < 4; ++p) {
            int row = p * 32 + arow;
            uint4 va = *(const uint4*)(A  + abase + (size_t)row * KDIM + k0 + acol);
            if (MODE == 2) {
                va.x = bnpack(va.x, sc0.x, sc0.y, sh0.x, sh0.y);
                va.y = bnpack(va.y, sc0.z, sc0.w, sh0.z, sh0.w);
                va.z = bnpack(va.z, sc1.x, sc1.y, sh1.x, sh1.y);
                va.w = bnpack(va.w, sc1.z, sc1.w, sh1.z, sh1.w);
            }
            *(uint4*)&As[row][acol] = va;
            uint4 vb = *(const uint4*)(BT + bbase + (size_t)row * KDIM + k0 + acol);
            *(uint4*)&Bs[row][acol] = vb;
        }
        __syncthreads();
        #pragma unroll
        for (int ks = 0; ks < 2; ++ks) {
            bf16x8 af[4], bfr[4];
            #pragma unroll
            for (int m = 0; m < 4; ++m)
                af[m] = *(const bf16x8*)&As[wr * 64 + m * 16 + l15][ks * 32 + l4 * 8];
            #pragma unroll
            for (int n = 0; n < 4; ++n)
                bfr[n] = *(const bf16x8*)&Bs[wc * 64 + n * 16 + l15][ks * 32 + l4 * 8];
            #pragma unroll
            for (int m = 0; m < 4; ++m)
                #pragma unroll
                for (int n = 0; n < 4; ++n)
                    acc[m][n] = __builtin_amdgcn_mfma_f32_16x16x32_bf16(af[m], bfr[n], acc[m][n], 0, 0, 0);
        }
        __syncthreads();
    }

    // epilogue: D row = (lane>>4)*4 + reg, col = lane&15   [m89-verified layout]
    float csum[4], csq[4];
    #pragma unroll
    for (int n = 0; n < 4; ++n) { csum[n] = 0.f; csq[n] = 0.f; }

    #pragma unroll
    for (int n = 0; n < 4; ++n) {
        int col = bn * 128 + wc * 64 + n * 16 + l15;
        float bv = bias[col];
        #pragma unroll
        for (int m = 0; m < 4; ++m) {
            int rbase = bm * 128 + wr * 64 + m * 16 + l4 * 4;
            #pragma unroll
            for (int i = 0; i < 4; ++i) {
                int grow = rbase + i;
                float vv = acc[m][n][i] + bv;
                if (MODE == 1) {
                    ((ushort*)out)[(size_t)grow * DOUT + col] = f2bf(vv);
                    if (grow < NNODES) { csum[n] += vv; csq[n] += vv * vv; }
                } else {
                    if (grow < NNODES)
                        ((float*)out)[(size_t)grow * DOUT + col] = vv;
                }
            }
        }
    }

    if (MODE == 1) {
        // per-block column reduce in LDS (reuse As), then 2 atomics/column
        float* sumarr = (float*)&As[0][0];       // 8 x 128
        float* sqarr  = sumarr + 1024;           // 8 x 128
        int cid = wr * 4 + l4;                   // 0..7, unique (cid,colL) writer
        #pragma unroll
        for (int n = 0; n < 4; ++n) {
            int colL = wc * 64 + n * 16 + l15;
            sumarr[cid * 128 + colL] = csum[n];
            sqarr [cid * 128 + colL] = csq[n];
        }
        __syncthreads();
        if (t < 128) {
            float s = 0.f, q = 0.f;
            #pragma unroll
            for (int k = 0; k < 8; ++k) { s += sumarr[k * 128 + t]; q += sqarr[k * 128 + t]; }
            atomicAdd(&gsum[bn * 128 + t], s);
            atomicAdd(&gsq [bn * 128 + t], q);
        }
    }
}

__global__ void k_bn_finalize(const float* __restrict__ sum, const float* __restrict__ sumsq,
                              const float* __restrict__ gamma, const float* __restrict__ beta,
                              float* __restrict__ scale, float* __restrict__ shift) {
    int c = threadIdx.x;                         // 512 threads
    float mean = sum[c] * (1.0f / NNODES);
    float var  = sumsq[c] * (1.0f / NNODES) - mean * mean;
    float sc   = gamma[c] * rsqrtf(var + BN_EPS);
    scale[c] = sc;
    shift[c] = beta[c] - mean * sc;
}

extern "C" void kernel_launch(void* const* d_in, const int* in_sizes, int n_in,
                              void* d_out, int out_size, void* d_ws, size_t ws_size,
                              hipStream_t stream) {
    const float* x     = (const float*)d_in[0];
    const int*   ei    = (const int*)  d_in[1];
    const float* ew    = (const float*)d_in[2];
    const float* W1    = (const float*)d_in[3];
    const float* b1    = (const float*)d_in[4];
    const float* gamma = (const float*)d_in[5];
    const float* beta  = (const float*)d_in[6];
    const float* W2    = (const float*)d_in[7];
    const float* b2    = (const float*)d_in[8];

    // ---- ws layout (~52 MB) ----
    char* ws = (char*)d_ws;
    ushort* h1b = (ushort*)ws;                       size_t off = (size_t)MP * DOUT * 2;
    ushort* W1T = (ushort*)(ws + off);               off += (size_t)DOUT * DIN * 2;
    ushort* W2T = (ushort*)(ws + off);               off += (size_t)DOUT * DOUT * 2;
    float* colsum   = (float*)(ws + off);            off += 512 * 4;   // colsum+colsumsq contiguous (1024 f32)
    float* colsumsq = (float*)(ws + off);            off += 512 * 4;
    float* scale    = (float*)(ws + off);            off += 512 * 4;
    float* shift    = (float*)(ws + off);            off += 512 * 4;

    // ---- d_out double-duty: h0b + CSR scratch, all dead before GEMM2 writes ----
    char* ob = (char*)d_out;
    ushort* h0b     = (ushort*)ob;                   size_t ooff = (size_t)MP * DIN * 2;
    int2*   cw      = (int2*)(ob + ooff);            ooff += (size_t)NEDGES * 8;
    int*    deg     = (int*)(ob + ooff);             ooff += (size_t)MP * 4;   // deg+cursor adjacent for k_zero
    int*    cursor  = (int*)(ob + ooff);             ooff += (size_t)MP * 4;
    int*    rowstart= (int*)(ob + ooff);             ooff += (size_t)MP * 4;
    int*    bsum    = (int*)(ob + ooff);             ooff += 256 * 4;
    int*    bofs    = (int*)(ob + ooff);             ooff += 256 * 4;
    float*  outp    = (float*)d_out;

    // init + weight prep
    k_zero<<<(2 * MP + 255) / 256, 256, 0, stream>>>(deg, colsum);
    k_transpose<<<dim3(DOUT / 32, DIN / 32),  256, 0, stream>>>(W1, W1T, DIN,  DOUT);
    k_transpose<<<dim3(DOUT / 32, DOUT / 32), 256, 0, stream>>>(W2, W2T, DOUT, DOUT);

    // CSR build
    k_count<<<NEDGES / 256, 256, 0, stream>>>(ei, deg);
    k_scan_block<<<NBLK, 256, 0, stream>>>(deg, rowstart, bsum);
    k_scan_bsum<<<1, 256, 0, stream>>>(bsum, bofs);
    k_bucket<<<NEDGES / 256, 256, 0, stream>>>(ei, ew, rowstart, bofs, cursor, cw);

    // aggregate (gather, no atomics) -> bf16
    k_aggregate<<<MP / 4, 256, 0, stream>>>(x, cw, rowstart, bofs, deg, h0b);

    // MLP: GEMM1 (+stats) -> finalize -> GEMM2 (BN+ReLU fused into A-staging)
    k_gemm<DIN, 1><<<(MP / 128) * 4, 256, 0, stream>>>(h0b, W1T, b1, nullptr, nullptr,
                                                       colsum, colsumsq, (void*)h1b);
    k_bn_finalize<<<1, 512, 0, stream>>>(colsum, colsumsq, gamma, beta, scale, shift);
    k_gemm<DOUT, 2><<<(MP / 128) * 4, 256, 0, stream>>>(h1b, W2T, b2, scale, shift,
                                                        nullptr, nullptr, (void*)outp);
}

// Round 5
// 438.115 us; speedup vs baseline: 6.8743x; 1.0510x over previous
//
#include <hip/hip_runtime.h>

#define NNODES 50000
#define NEDGES 800000
#define DIN    256
#define DOUT   512
#define MP     50048          // ceil(NNODES/128)*128
#define BN_EPS 1e-5f
#define NBLK   196            // ceil(NNODES/256) scan blocks

// k_prep grid segmentation
#define CVT_B  6250           // NNODES*DIN/8/256
#define ZERO_B 391            // 2*MP / 256
#define T1_B   128            // (DOUT/32)*(DIN/32)
#define T2_B   256            // (DOUT/32)*(DOUT/32)
#define PREP_B (CVT_B + ZERO_B + T1_B + T2_B)

typedef __attribute__((ext_vector_type(8))) __bf16 bf16x8;
typedef __attribute__((ext_vector_type(4))) float  floatx4;

__device__ __forceinline__ ushort f2bf(float f) {
    union { float f; uint u; } v; v.f = f;
    uint u = v.u;
    return (ushort)((u + 0x7FFFu + ((u >> 16) & 1u)) >> 16);   // RNE
}
__device__ __forceinline__ float bf2f(ushort b) {
    union { uint u; float f; } v; v.u = ((uint)b) << 16;
    return v.f;
}
// BN+ReLU on a packed pair of bf16 while staging
__device__ __forceinline__ uint bnpack(uint u, float s0, float s1, float h0, float h1) {
    float a = bf2f((ushort)(u & 0xffff)) * s0 + h0;
    float b = bf2f((ushort)(u >> 16))    * s1 + h1;
    a = fmaxf(a, 0.f); b = fmaxf(b, 0.f);
    return (uint)f2bf(a) | ((uint)f2bf(b) << 16);
}

// ---------------- fused prep: x->bf16 | zero deg/cursor/stats | W1^T | W2^T ----------------
__global__ __launch_bounds__(256) void k_prep(const float* __restrict__ x, ushort* __restrict__ xb,
                                              const float* __restrict__ W1, ushort* __restrict__ W1T,
                                              const float* __restrict__ W2, ushort* __restrict__ W2T,
                                              int* __restrict__ zi, float* __restrict__ zf) {
    __shared__ float tile[32][33];
    int b = blockIdx.x;
    int t = threadIdx.x;
    if (b < CVT_B) {                              // x (f32) -> xb (bf16), 8 elems/thread
        size_t base = ((size_t)b * 256 + t) * 8;
        float4 v0 = *(const float4*)(x + base);
        float4 v1 = *(const float4*)(x + base + 4);
        uint4 o;
        o.x = (uint)f2bf(v0.x) | ((uint)f2bf(v0.y) << 16);
        o.y = (uint)f2bf(v0.z) | ((uint)f2bf(v0.w) << 16);
        o.z = (uint)f2bf(v1.x) | ((uint)f2bf(v1.y) << 16);
        o.w = (uint)f2bf(v1.z) | ((uint)f2bf(v1.w) << 16);
        *(uint4*)(xb + base) = o;
        return;
    }
    b -= CVT_B;
    if (b < ZERO_B) {                             // zero deg+cursor (2*MP) and colsum/colsumsq (1024)
        int i = b * 256 + t;
        if (i < 2 * MP) zi[i] = 0;
        if (i < 1024)   zf[i] = 0.f;
        return;
    }
    b -= ZERO_B;
    const float* W; ushort* WT; int K, Nc, bx, by;
    if (b < T1_B) { W = W1; WT = W1T; K = DIN;  Nc = DOUT; bx = b & 15; by = b >> 4; }
    else { b -= T1_B; W = W2; WT = W2T; K = DOUT; Nc = DOUT; bx = b & 15; by = b >> 4; }
    int lx = t & 31, ly = t >> 5;
    #pragma unroll
    for (int p = 0; p < 4; ++p)
        tile[ly + p * 8][lx] = W[(size_t)(by * 32 + ly + p * 8) * Nc + bx * 32 + lx];
    __syncthreads();
    #pragma unroll
    for (int p = 0; p < 4; ++p)
        WT[(size_t)(bx * 32 + ly + p * 8) * K + by * 32 + lx] = f2bf(tile[lx][ly + p * 8]);
}

// ---------------- CSR build ----------------
__global__ void k_count(const int* __restrict__ ei, int* __restrict__ deg) {
    int e = blockIdx.x * 256 + threadIdx.x;
    atomicAdd(&deg[ei[e]], 1);
}

__global__ void k_scan_block(const int* __restrict__ deg, int* __restrict__ rowstart,
                             int* __restrict__ bsum) {
    __shared__ int s[256];
    int t = threadIdx.x;
    int i = blockIdx.x * 256 + t;
    int v = (i < NNODES) ? deg[i] : 0;
    s[t] = v; __syncthreads();
    #pragma unroll
    for (int d = 1; d < 256; d <<= 1) {
        int add = (t >= d) ? s[t - d] : 0;
        __syncthreads();
        s[t] += add;
        __syncthreads();
    }
    if (i < MP) rowstart[i] = s[t] - v;          // exclusive, block-local
    if (t == 255) bsum[blockIdx.x] = s[255];
}

__global__ void k_scan_bsum(const int* __restrict__ bsum, int* __restrict__ bofs) {
    __shared__ int s[256];
    int t = threadIdx.x;
    int v = (t < NBLK) ? bsum[t] : 0;
    s[t] = v; __syncthreads();
    #pragma unroll
    for (int d = 1; d < 256; d <<= 1) {
        int add = (t >= d) ? s[t - d] : 0;
        __syncthreads();
        s[t] += add;
        __syncthreads();
    }
    bofs[t] = s[t] - v;
}

__global__ void k_bucket(const int* __restrict__ ei, const float* __restrict__ ew,
                         const int* __restrict__ rowstart, const int* __restrict__ bofs,
                         int* __restrict__ cursor, int2* __restrict__ cw) {
    int e = blockIdx.x * 256 + threadIdx.x;
    int r = ei[e];
    int c = ei[NEDGES + e];
    float w = ew[e];
    int pos = rowstart[r] + bofs[r >> 8] + atomicAdd(&cursor[r], 1);
    cw[pos] = make_int2(c, __float_as_int(w));
}

// ---------------- gather-aggregate from bf16 x: h0b[n] = bf16( x[n] + sum w_e * x[col_e] ) ----------------
// one wave per node, lane owns 4 columns (8B ushort4 loads); 4x unrolled
__global__ __launch_bounds__(256) void k_aggregate(const ushort* __restrict__ xb,
                                                   const int2* __restrict__ cw,
                                                   const int* __restrict__ rowstart,
                                                   const int* __restrict__ bofs,
                                                   const int* __restrict__ deg,
                                                   ushort* __restrict__ h0b) {
    int t = threadIdx.x;
    int wv = t >> 6, lane = t & 63;
    int n = blockIdx.x * 4 + wv;
    if (n >= MP) return;
    ushort* dst = h0b + (size_t)n * DIN + lane * 4;
    if (n >= NNODES) {                           // zero the pad rows
        *(ushort4*)dst = make_ushort4(0, 0, 0, 0);
        return;
    }
    const ushort* xl = xb + lane * 4;
    ushort4 sd = *(const ushort4*)(xl + (size_t)n * DIN);
    float4 acc = make_float4(bf2f(sd.x), bf2f(sd.y), bf2f(sd.z), bf2f(sd.w));
    int start = rowstart[n] + bofs[n >> 8];
    int end   = start + deg[n];
    int j = start;
    for (; j + 3 < end; j += 4) {
        int2 e0 = cw[j], e1 = cw[j + 1], e2 = cw[j + 2], e3 = cw[j + 3];
        ushort4 v0 = *(const ushort4*)(xl + (size_t)e0.x * DIN);
        ushort4 v1 = *(const ushort4*)(xl + (size_t)e1.x * DIN);
        ushort4 v2 = *(const ushort4*)(xl + (size_t)e2.x * DIN);
        ushort4 v3 = *(const ushort4*)(xl + (size_t)e3.x * DIN);
        float w0 = __int_as_float(e0.y), w1 = __int_as_float(e1.y);
        float w2 = __int_as_float(e2.y), w3 = __int_as_float(e3.y);
        acc.x += w0 * bf2f(v0.x); acc.y += w0 * bf2f(v0.y); acc.z += w0 * bf2f(v0.z); acc.w += w0 * bf2f(v0.w);
        acc.x += w1 * bf2f(v1.x); acc.y += w1 * bf2f(v1.y); acc.z += w1 * bf2f(v1.z); acc.w += w1 * bf2f(v1.w);
        acc.x += w2 * bf2f(v2.x); acc.y += w2 * bf2f(v2.y); acc.z += w2 * bf2f(v2.z); acc.w += w2 * bf2f(v2.w);
        acc.x += w3 * bf2f(v3.x); acc.y += w3 * bf2f(v3.y); acc.z += w3 * bf2f(v3.z); acc.w += w3 * bf2f(v3.w);
    }
    for (; j < end; ++j) {
        int2 cv = cw[j];
        float w = __int_as_float(cv.y);
        ushort4 v = *(const ushort4*)(xl + (size_t)cv.x * DIN);
        acc.x += w * bf2f(v.x); acc.y += w * bf2f(v.y); acc.z += w * bf2f(v.z); acc.w += w * bf2f(v.w);
    }
    ushort4 o;
    o.x = f2bf(acc.x); o.y = f2bf(acc.y); o.z = f2bf(acc.z); o.w = f2bf(acc.w);
    *(ushort4*)dst = o;
}

// ---------------- bf16 MFMA GEMM: C = A @ BT^T + bias ----------------
// MODE 1 (GEMM1): bf16 out (all MP rows) + fused BN-stats column reduction into gsum/gsq
// MODE 2 (GEMM2): BN scale/shift computed inline from gsum/gsq/gamma/beta, applied to A
//                 during staging (+ReLU); f32 out, row<NNODES guard
template<int KDIM, int MODE>
__global__ __launch_bounds__(256) void k_gemm(const ushort* __restrict__ A,
                                              const ushort* __restrict__ BT,
                                              const float* __restrict__ bias,
                                              const float* __restrict__ gamma,
                                              const float* __restrict__ beta,
                                              float* __restrict__ gsum,
                                              float* __restrict__ gsq,
                                              void* __restrict__ out) {
    constexpr int LDSK = 64 + 8;                 // +8 bf16 pad: ~2-way-max bank aliasing on b128 reads
    __shared__ ushort As[128][LDSK];
    __shared__ ushort Bs[128][LDSK];

    int t    = threadIdx.x;
    int bm   = blockIdx.x >> 2;
    int bn   = blockIdx.x & 3;
    int lane = t & 63;
    int w    = t >> 6;
    int wr   = w >> 1, wc = w & 1;               // 2x2 waves -> 64x64 each
    int l15  = lane & 15, l4 = lane >> 4;

    floatx4 acc[4][4] = {};

    int arow = t >> 3;                           // 0..31
    int acol = (t & 7) * 8;                      // 0..56
    const size_t abase = (size_t)(bm * 128) * KDIM;
    const size_t bbase = (size_t)(bn * 128) * KDIM;

    for (int k0 = 0; k0 < KDIM; k0 += 64) {
        float scl[8], shf[8];
        if (MODE == 2) {
            #pragma unroll
            for (int jj = 0; jj < 8; ++jj) {     // inline BN finalize for this staging column slice
                int c = k0 + acol + jj;
                float mean = gsum[c] * (1.0f / NNODES);
                float var  = gsq[c]  * (1.0f / NNODES) - mean * mean;
                float s    = gamma[c] * rsqrtf(var + BN_EPS);
                scl[jj] = s;
                shf[jj] = beta[c] - mean * s;
            }
        }
        #pragma unroll
        for (int p = 0; p < 4; ++p) {
            int row = p * 32 + arow;
            uint4 va = *(const uint4*)(A  + abase + (size_t)row * KDIM + k0 + acol);
            if (MODE == 2) {
                va.x = bnpack(va.x, scl[0], scl[1], shf[0], shf[1]);
                va.y = bnpack(va.y, scl[2], scl[3], shf[2], shf[3]);
                va.z = bnpack(va.z, scl[4], scl[5], shf[4], shf[5]);
                va.w = bnpack(va.w, scl[6], scl[7], shf[6], shf[7]);
            }
            *(uint4*)&As[row][acol] = va;
            uint4 vb = *(const uint4*)(BT + bbase + (size_t)row * KDIM + k0 + acol);
            *(uint4*)&Bs[row][acol] = vb;
        }
        __syncthreads();
        #pragma unroll
        for (int ks = 0; ks < 2; ++ks) {
            bf16x8 af[4], bfr[4];
            #pragma unroll
            for (int m = 0; m < 4; ++m)
                af[m] = *(const bf16x8*)&As[wr * 64 + m * 16 + l15][ks * 32 + l4 * 8];
            #pragma unroll
            for (int n = 0; n < 4; ++n)
                bfr[n] = *(const bf16x8*)&Bs[wc * 64 + n * 16 + l15][ks * 32 + l4 * 8];
            #pragma unroll
            for (int m = 0; m < 4; ++m)
                #pragma unroll
                for (int n = 0; n < 4; ++n)
                    acc[m][n] = __builtin_amdgcn_mfma_f32_16x16x32_bf16(af[m], bfr[n], acc[m][n], 0, 0, 0);
        }
        __syncthreads();
    }

    // epilogue: D row = (lane>>4)*4 + reg, col = lane&15   [m89-verified layout]
    float csum[4], csq[4];
    #pragma unroll
    for (int n = 0; n < 4; ++n) { csum[n] = 0.f; csq[n] = 0.f; }

    #pragma unroll
    for (int n = 0; n < 4; ++n) {
        int col = bn * 128 + wc * 64 + n * 16 + l15;
        float bv = bias[col];
        #pragma unroll
        for (int m = 0; m < 4; ++m) {
            int rbase = bm * 128 + wr * 64 + m * 16 + l4 * 4;
            #pragma unroll
            for (int i = 0; i < 4; ++i) {
                int grow = rbase + i;
                float vv = acc[m][n][i] + bv;
                if (MODE == 1) {
                    ((ushort*)out)[(size_t)grow * DOUT + col] = f2bf(vv);
                    if (grow < NNODES) { csum[n] += vv; csq[n] += vv * vv; }
                } else {
                    if (grow < NNODES)
                        ((float*)out)[(size_t)grow * DOUT + col] = vv;
                }
            }
        }
    }

    if (MODE == 1) {
        // per-block column reduce in LDS (reuse As), then 2 atomics/column
        float* sumarr = (float*)&As[0][0];       // 8 x 128
        float* sqarr  = sumarr + 1024;           // 8 x 128
        int cid = wr * 4 + l4;                   // 0..7, unique (cid,colL) writer
        #pragma unroll
        for (int n = 0; n < 4; ++n) {
            int colL = wc * 64 + n * 16 + l15;
            sumarr[cid * 128 + colL] = csum[n];
            sqarr [cid * 128 + colL] = csq[n];
        }
        __syncthreads();
        if (t < 128) {
            float s = 0.f, q = 0.f;
            #pragma unroll
            for (int k = 0; k < 8; ++k) { s += sumarr[k * 128 + t]; q += sqarr[k * 128 + t]; }
            atomicAdd(&gsum[bn * 128 + t], s);
            atomicAdd(&gsq [bn * 128 + t], q);
        }
    }
}

extern "C" void kernel_launch(void* const* d_in, const int* in_sizes, int n_in,
                              void* d_out, int out_size, void* d_ws, size_t ws_size,
                              hipStream_t stream) {
    const float* x     = (const float*)d_in[0];
    const int*   ei    = (const int*)  d_in[1];
    const float* ew    = (const float*)d_in[2];
    const float* W1    = (const float*)d_in[3];
    const float* b1    = (const float*)d_in[4];
    const float* gamma = (const float*)d_in[5];
    const float* beta  = (const float*)d_in[6];
    const float* W2    = (const float*)d_in[7];
    const float* b2    = (const float*)d_in[8];

    // ---- ws layout (~52 MB) ----
    char* ws = (char*)d_ws;
    ushort* h1b = (ushort*)ws;                       size_t off = (size_t)MP * DOUT * 2;
    ushort* W1T = (ushort*)(ws + off);               off += (size_t)DOUT * DIN * 2;
    ushort* W2T = (ushort*)(ws + off);               off += (size_t)DOUT * DOUT * 2;
    float* colsum   = (float*)(ws + off);            off += 512 * 4;   // colsum+colsumsq contiguous (1024 f32)
    float* colsumsq = (float*)(ws + off);            off += 512 * 4;

    // ---- d_out double-duty: h0b + xb + CSR scratch, all dead before GEMM2 writes ----
    char* ob = (char*)d_out;
    ushort* h0b     = (ushort*)ob;                   size_t ooff = (size_t)MP * DIN * 2;
    ushort* xb      = (ushort*)(ob + ooff);          ooff += (size_t)NNODES * DIN * 2;
    int2*   cw      = (int2*)(ob + ooff);            ooff += (size_t)NEDGES * 8;
    int*    deg     = (int*)(ob + ooff);             ooff += (size_t)MP * 4;   // deg+cursor adjacent for zeroing
    int*    cursor  = (int*)(ob + ooff);             ooff += (size_t)MP * 4;
    int*    rowstart= (int*)(ob + ooff);             ooff += (size_t)MP * 4;
    int*    bsum    = (int*)(ob + ooff);             ooff += 256 * 4;
    int*    bofs    = (int*)(ob + ooff);             ooff += 256 * 4;
    float*  outp    = (float*)d_out;

    // fused prep: x->bf16, zero deg/cursor/stats, transpose W1/W2 to bf16
    k_prep<<<PREP_B, 256, 0, stream>>>(x, xb, W1, W1T, W2, W2T, deg, colsum);

    // CSR build
    k_count<<<NEDGES / 256, 256, 0, stream>>>(ei, deg);
    k_scan_block<<<NBLK, 256, 0, stream>>>(deg, rowstart, bsum);
    k_scan_bsum<<<1, 256, 0, stream>>>(bsum, bofs);
    k_bucket<<<NEDGES / 256, 256, 0, stream>>>(ei, ew, rowstart, bofs, cursor, cw);

    // aggregate (bf16 gather, no atomics) -> bf16
    k_aggregate<<<MP / 4, 256, 0, stream>>>(xb, cw, rowstart, bofs, deg, h0b);

    // MLP: GEMM1 (+stats) -> GEMM2 (inline BN finalize + BN/ReLU fused into A-staging)
    k_gemm<DIN, 1><<<(MP / 128) * 4, 256, 0, stream>>>(h0b, W1T, b1, nullptr, nullptr,
                                                       colsum, colsumsq, (void*)h1b);
    k_gemm<DOUT, 2><<<(MP / 128) * 4, 256, 0, stream>>>(h1b, W2T, b2, gamma, beta,
                                                        colsum, colsumsq, (void*)outp);
}

// Round 6
// 417.302 us; speedup vs baseline: 7.2172x; 1.0499x over previous
//
#include <hip/hip_runtime.h>

#define NNODES 50000
#define NEDGES 800000
#define DIN    256
#define DOUT   512
#define MP     50048          // ceil(NNODES/128)*128
#define BN_EPS 1e-5f
#define NBLK   196            // ceil(NNODES/256) scan blocks

// k_prep grid segmentation
#define CVT_B  6250           // NNODES*DIN/8/256
#define ZERO_B 391            // 2*MP / 256
#define T1_B   128            // (DOUT/32)*(DIN/32)
#define T2_B   256            // (DOUT/32)*(DOUT/32)
#define PREP_B (CVT_B + ZERO_B + T1_B + T2_B)

typedef __attribute__((ext_vector_type(8))) __bf16 bf16x8;
typedef __attribute__((ext_vector_type(4))) float  floatx4;

// f32 pair -> packed bf16 (compiler emits v_cvt_pk_bf16_f32)
__device__ __forceinline__ uint pkbf(float a, float b) {
    union { __bf16 h[2]; uint u; } cv;
    cv.h[0] = (__bf16)a; cv.h[1] = (__bf16)b;
    return cv.u;
}
__device__ __forceinline__ ushort f2bf(float f) {
    union { __bf16 h; ushort u; } cv;
    cv.h = (__bf16)f;
    return cv.u;
}
__device__ __forceinline__ float bf2f(ushort b) {
    union { uint u; float f; } v; v.u = ((uint)b) << 16;
    return v.f;
}
// BN+ReLU on a packed pair of bf16 while staging
__device__ __forceinline__ uint bnpack(uint u, float s0, float s1, float h0, float h1) {
    float a = fmaxf(bf2f((ushort)(u & 0xffff)) * s0 + h0, 0.f);
    float b = fmaxf(bf2f((ushort)(u >> 16))    * s1 + h1, 0.f);
    return pkbf(a, b);
}

// ---------------- fused prep: x->bf16 | zero deg/cursor/stats | W1^T | W2^T ----------------
__global__ __launch_bounds__(256) void k_prep(const float* __restrict__ x, ushort* __restrict__ xb,
                                              const float* __restrict__ W1, ushort* __restrict__ W1T,
                                              const float* __restrict__ W2, ushort* __restrict__ W2T,
                                              int* __restrict__ zi, float* __restrict__ zf) {
    __shared__ float tile[32][33];
    int b = blockIdx.x;
    int t = threadIdx.x;
    if (b < CVT_B) {                              // x (f32) -> xb (bf16), 8 elems/thread
        size_t base = ((size_t)b * 256 + t) * 8;
        float4 v0 = *(const float4*)(x + base);
        float4 v1 = *(const float4*)(x + base + 4);
        uint4 o;
        o.x = pkbf(v0.x, v0.y);
        o.y = pkbf(v0.z, v0.w);
        o.z = pkbf(v1.x, v1.y);
        o.w = pkbf(v1.z, v1.w);
        *(uint4*)(xb + base) = o;
        return;
    }
    b -= CVT_B;
    if (b < ZERO_B) {                             // zero deg+cursor (2*MP) and colsum/colsumsq (1024)
        int i = b * 256 + t;
        if (i < 2 * MP) zi[i] = 0;
        if (i < 1024)   zf[i] = 0.f;
        return;
    }
    b -= ZERO_B;
    const float* W; ushort* WT; int K, Nc, bx, by;
    if (b < T1_B) { W = W1; WT = W1T; K = DIN;  Nc = DOUT; bx = b & 15; by = b >> 4; }
    else { b -= T1_B; W = W2; WT = W2T; K = DOUT; Nc = DOUT; bx = b & 15; by = b >> 4; }
    int lx = t & 31, ly = t >> 5;
    #pragma unroll
    for (int p = 0; p < 4; ++p)
        tile[ly + p * 8][lx] = W[(size_t)(by * 32 + ly + p * 8) * Nc + bx * 32 + lx];
    __syncthreads();
    #pragma unroll
    for (int p = 0; p < 4; ++p)
        WT[(size_t)(bx * 32 + ly + p * 8) * K + by * 32 + lx] = f2bf(tile[lx][ly + p * 8]);
}

// ---------------- CSR build ----------------
__global__ void k_count(const int* __restrict__ ei, int* __restrict__ deg) {
    int e = blockIdx.x * 256 + threadIdx.x;
    atomicAdd(&deg[ei[e]], 1);
}

__global__ void k_scan_block(const int* __restrict__ deg, int* __restrict__ rowstart,
                             int* __restrict__ bsum) {
    __shared__ int s[256];
    int t = threadIdx.x;
    int i = blockIdx.x * 256 + t;
    int v = (i < NNODES) ? deg[i] : 0;
    s[t] = v; __syncthreads();
    #pragma unroll
    for (int d = 1; d < 256; d <<= 1) {
        int add = (t >= d) ? s[t - d] : 0;
        __syncthreads();
        s[t] += add;
        __syncthreads();
    }
    if (i < MP) rowstart[i] = s[t] - v;          // exclusive, block-local
    if (t == 255) bsum[blockIdx.x] = s[255];
}

__global__ void k_scan_bsum(const int* __restrict__ bsum, int* __restrict__ bofs) {
    __shared__ int s[256];
    int t = threadIdx.x;
    int v = (t < NBLK) ? bsum[t] : 0;
    s[t] = v; __syncthreads();
    #pragma unroll
    for (int d = 1; d < 256; d <<= 1) {
        int add = (t >= d) ? s[t - d] : 0;
        __syncthreads();
        s[t] += add;
        __syncthreads();
    }
    bofs[t] = s[t] - v;
}

__global__ void k_bucket(const int* __restrict__ ei, const float* __restrict__ ew,
                         const int* __restrict__ rowstart, const int* __restrict__ bofs,
                         int* __restrict__ cursor, int2* __restrict__ cw) {
    int e = blockIdx.x * 256 + threadIdx.x;
    int r = ei[e];
    int c = ei[NEDGES + e];
    float w = ew[e];
    int pos = rowstart[r] + bofs[r >> 8] + atomicAdd(&cursor[r], 1);
    cw[pos] = make_int2(c, __float_as_int(w));
}

// ---------------- gather-aggregate from bf16 x: h0b[n] = bf16( x[n] + sum w_e * x[col_e] ) ----------------
__global__ __launch_bounds__(256) void k_aggregate(const ushort* __restrict__ xb,
                                                   const int2* __restrict__ cw,
                                                   const int* __restrict__ rowstart,
                                                   const int* __restrict__ bofs,
                                                   const int* __restrict__ deg,
                                                   ushort* __restrict__ h0b) {
    int t = threadIdx.x;
    int wv = t >> 6, lane = t & 63;
    int n = blockIdx.x * 4 + wv;
    if (n >= MP) return;
    ushort* dst = h0b + (size_t)n * DIN + lane * 4;
    if (n >= NNODES) {                           // zero the pad rows
        *(ushort4*)dst = make_ushort4(0, 0, 0, 0);
        return;
    }
    const ushort* xl = xb + lane * 4;
    ushort4 sd = *(const ushort4*)(xl + (size_t)n * DIN);
    float4 acc = make_float4(bf2f(sd.x), bf2f(sd.y), bf2f(sd.z), bf2f(sd.w));
    int start = rowstart[n] + bofs[n >> 8];
    int end   = start + deg[n];
    int j = start;
    for (; j + 3 < end; j += 4) {
        int2 e0 = cw[j], e1 = cw[j + 1], e2 = cw[j + 2], e3 = cw[j + 3];
        ushort4 v0 = *(const ushort4*)(xl + (size_t)e0.x * DIN);
        ushort4 v1 = *(const ushort4*)(xl + (size_t)e1.x * DIN);
        ushort4 v2 = *(const ushort4*)(xl + (size_t)e2.x * DIN);
        ushort4 v3 = *(const ushort4*)(xl + (size_t)e3.x * DIN);
        float w0 = __int_as_float(e0.y), w1 = __int_as_float(e1.y);
        float w2 = __int_as_float(e2.y), w3 = __int_as_float(e3.y);
        acc.x += w0 * bf2f(v0.x); acc.y += w0 * bf2f(v0.y); acc.z += w0 * bf2f(v0.z); acc.w += w0 * bf2f(v0.w);
        acc.x += w1 * bf2f(v1.x); acc.y += w1 * bf2f(v1.y); acc.z += w1 * bf2f(v1.z); acc.w += w1 * bf2f(v1.w);
        acc.x += w2 * bf2f(v2.x); acc.y += w2 * bf2f(v2.y); acc.z += w2 * bf2f(v2.z); acc.w += w2 * bf2f(v2.w);
        acc.x += w3 * bf2f(v3.x); acc.y += w3 * bf2f(v3.y); acc.z += w3 * bf2f(v3.z); acc.w += w3 * bf2f(v3.w);
    }
    for (; j < end; ++j) {
        int2 cv = cw[j];
        float w = __int_as_float(cv.y);
        ushort4 v = *(const ushort4*)(xl + (size_t)cv.x * DIN);
        acc.x += w * bf2f(v.x); acc.y += w * bf2f(v.y); acc.z += w * bf2f(v.z); acc.w += w * bf2f(v.w);
    }
    uint2 o;
    o.x = pkbf(acc.x, acc.y);
    o.y = pkbf(acc.z, acc.w);
    *(uint2*)dst = o;
}

// ---------------- bf16 MFMA GEMM: C = A @ BT^T + bias ----------------
// MODE 1 (GEMM1): bf16 out (all MP rows) + fused BN-stats column reduction into gsum/gsq
// MODE 2 (GEMM2): precomputed BN scale/shift applied to A during staging (+ReLU);
//                 f32 out, row<NNODES guard
template<int KDIM, int MODE>
__global__ __launch_bounds__(256) void k_gemm(const ushort* __restrict__ A,
                                              const ushort* __restrict__ BT,
                                              const float* __restrict__ bias,
                                              const float* __restrict__ scale,
                                              const float* __restrict__ shift,
                                              float* __restrict__ gsum,
                                              float* __restrict__ gsq,
                                              void* __restrict__ out) {
    constexpr int LDSK = 64 + 8;                 // +8 bf16 pad: near-minimal aliasing on b128 r/w
    __shared__ ushort As[128][LDSK];
    __shared__ ushort Bs[128][LDSK];

    int t    = threadIdx.x;
    int bm   = blockIdx.x >> 2;
    int bn   = blockIdx.x & 3;
    int lane = t & 63;
    int w    = t >> 6;
    int wr   = w >> 1, wc = w & 1;               // 2x2 waves -> 64x64 each
    int l15  = lane & 15, l4 = lane >> 4;

    floatx4 acc[4][4] = {};

    int arow = t >> 3;                           // 0..31
    int acol = (t & 7) * 8;                      // 0..56
    const size_t abase = (size_t)(bm * 128) * KDIM;
    const size_t bbase = (size_t)(bn * 128) * KDIM;

    for (int k0 = 0; k0 < KDIM; k0 += 64) {
        float4 sc0, sc1, sh0, sh1;
        if (MODE == 2) {                         // 4 vector loads of precomputed scale/shift
            sc0 = *(const float4*)(scale + k0 + acol);
            sc1 = *(const float4*)(scale + k0 + acol + 4);
            sh0 = *(const float4*)(shift + k0 + acol);
            sh1 = *(const float4*)(shift + k0 + acol + 4);
        }
        #pragma unroll
        for (int p = 0; p < 4; ++p) {
            int row = p * 32 + arow;
            uint4 va = *(const uint4*)(A  + abase + (size_t)row * KDIM + k0 + acol);
            if (MODE == 2) {
                va.x = bnpack(va.x, sc0.x, sc0.y, sh0.x, sh0.y);
                va.y = bnpack(va.y, sc0.z, sc0.w, sh0.z, sh0.w);
                va.z = bnpack(va.z, sc1.x, sc1.y, sh1.x, sh1.y);
                va.w = bnpack(va.w, sc1.z, sc1.w, sh1.z, sh1.w);
            }
            *(uint4*)&As[row][acol] = va;
            uint4 vb = *(const uint4*)(BT + bbase + (size_t)row * KDIM + k0 + acol);
            *(uint4*)&Bs[row][acol] = vb;
        }
        __syncthreads();
        #pragma unroll
        for (int ks = 0; ks < 2; ++ks) {
            bf16x8 af[4], bfr[4];
            #pragma unroll
            for (int m = 0; m < 4; ++m)
                af[m] = *(const bf16x8*)&As[wr * 64 + m * 16 + l15][ks * 32 + l4 * 8];
            #pragma unroll
            for (int n = 0; n < 4; ++n)
                bfr[n] = *(const bf16x8*)&Bs[wc * 64 + n * 16 + l15][ks * 32 + l4 * 8];
            #pragma unroll
            for (int m = 0; m < 4; ++m)
                #pragma unroll
                for (int n = 0; n < 4; ++n)
                    acc[m][n] = __builtin_amdgcn_mfma_f32_16x16x32_bf16(af[m], bfr[n], acc[m][n], 0, 0, 0);
        }
        __syncthreads();
    }

    // epilogue: D row = (lane>>4)*4 + reg, col = lane&15   [m89-verified layout]
    float csum[4], csq[4];
    #pragma unroll
    for (int n = 0; n < 4; ++n) { csum[n] = 0.f; csq[n] = 0.f; }

    #pragma unroll
    for (int n = 0; n < 4; ++n) {
        int col = bn * 128 + wc * 64 + n * 16 + l15;
        float bv = bias[col];
        #pragma unroll
        for (int m = 0; m < 4; ++m) {
            int rbase = bm * 128 + wr * 64 + m * 16 + l4 * 4;
            #pragma unroll
            for (int i = 0; i < 4; ++i) {
                int grow = rbase + i;
                float vv = acc[m][n][i] + bv;
                if (MODE == 1) {
                    ((ushort*)out)[(size_t)grow * DOUT + col] = f2bf(vv);
                    if (grow < NNODES) { csum[n] += vv; csq[n] += vv * vv; }
                } else {
                    if (grow < NNODES)
                        ((float*)out)[(size_t)grow * DOUT + col] = vv;
                }
            }
        }
    }

    if (MODE == 1) {
        // per-block column reduce in LDS (reuse As), then 2 atomics/column
        float* sumarr = (float*)&As[0][0];       // 8 x 128
        float* sqarr  = sumarr + 1024;           // 8 x 128
        int cid = wr * 4 + l4;                   // 0..7, unique (cid,colL) writer
        #pragma unroll
        for (int n = 0; n < 4; ++n) {
            int colL = wc * 64 + n * 16 + l15;
            sumarr[cid * 128 + colL] = csum[n];
            sqarr [cid * 128 + colL] = csq[n];
        }
        __syncthreads();
        if (t < 128) {
            float s = 0.f, q = 0.f;
            #pragma unroll
            for (int k = 0; k < 8; ++k) { s += sumarr[k * 128 + t]; q += sqarr[k * 128 + t]; }
            atomicAdd(&gsum[bn * 128 + t], s);
            atomicAdd(&gsq [bn * 128 + t], q);
        }
    }
}

__global__ void k_bn_finalize(const float* __restrict__ sum, const float* __restrict__ sumsq,
                              const float* __restrict__ gamma, const float* __restrict__ beta,
                              float* __restrict__ scale, float* __restrict__ shift) {
    int c = threadIdx.x;                         // 512 threads
    float mean = sum[c] * (1.0f / NNODES);
    float var  = sumsq[c] * (1.0f / NNODES) - mean * mean;
    float sc   = gamma[c] * rsqrtf(var + BN_EPS);
    scale[c] = sc;
    shift[c] = beta[c] - mean * sc;
}

extern "C" void kernel_launch(void* const* d_in, const int* in_sizes, int n_in,
                              void* d_out, int out_size, void* d_ws, size_t ws_size,
                              hipStream_t stream) {
    const float* x     = (const float*)d_in[0];
    const int*   ei    = (const int*)  d_in[1];
    const float* ew    = (const float*)d_in[2];
    const float* W1    = (const float*)d_in[3];
    const float* b1    = (const float*)d_in[4];
    const float* gamma = (const float*)d_in[5];
    const float* beta  = (const float*)d_in[6];
    const float* W2    = (const float*)d_in[7];
    const float* b2    = (const float*)d_in[8];

    // ---- ws layout (~52 MB) ----
    char* ws = (char*)d_ws;
    ushort* h1b = (ushort*)ws;                       size_t off = (size_t)MP * DOUT * 2;
    ushort* W1T = (ushort*)(ws + off);               off += (size_t)DOUT * DIN * 2;
    ushort* W2T = (ushort*)(ws + off);               off += (size_t)DOUT * DOUT * 2;
    float* colsum   = (float*)(ws + off);            off += 512 * 4;   // colsum+colsumsq contiguous (1024 f32)
    float* colsumsq = (float*)(ws + off);            off += 512 * 4;
    float* scale    = (float*)(ws + off);            off += 512 * 4;
    float* shift    = (float*)(ws + off);            off += 512 * 4;

    // ---- d_out double-duty: h0b + xb + CSR scratch, all dead before GEMM2 writes ----
    char* ob = (char*)d_out;
    ushort* h0b     = (ushort*)ob;                   size_t ooff = (size_t)MP * DIN * 2;
    ushort* xb      = (ushort*)(ob + ooff);          ooff += (size_t)NNODES * DIN * 2;
    int2*   cw      = (int2*)(ob + ooff);            ooff += (size_t)NEDGES * 8;
    int*    deg     = (int*)(ob + ooff);             ooff += (size_t)MP * 4;   // deg+cursor adjacent for zeroing
    int*    cursor  = (int*)(ob + ooff);             ooff += (size_t)MP * 4;
    int*    rowstart= (int*)(ob + ooff);             ooff += (size_t)MP * 4;
    int*    bsum    = (int*)(ob + ooff);             ooff += 256 * 4;
    int*    bofs    = (int*)(ob + ooff);             ooff += 256 * 4;
    float*  outp    = (float*)d_out;

    // fused prep: x->bf16, zero deg/cursor/stats, transpose W1/W2 to bf16
    k_prep<<<PREP_B, 256, 0, stream>>>(x, xb, W1, W1T, W2, W2T, deg, colsum);

    // CSR build
    k_count<<<NEDGES / 256, 256, 0, stream>>>(ei, deg);
    k_scan_block<<<NBLK, 256, 0, stream>>>(deg, rowstart, bsum);
    k_scan_bsum<<<1, 256, 0, stream>>>(bsum, bofs);
    k_bucket<<<NEDGES / 256, 256, 0, stream>>>(ei, ew, rowstart, bofs, cursor, cw);

    // aggregate (bf16 gather, no atomics) -> bf16
    k_aggregate<<<MP / 4, 256, 0, stream>>>(xb, cw, rowstart, bofs, deg, h0b);

    // MLP: GEMM1 (+stats) -> tiny finalize -> GEMM2 (BN/ReLU fused into A-staging)
    k_gemm<DIN, 1><<<(MP / 128) * 4, 256, 0, stream>>>(h0b, W1T, b1, nullptr, nullptr,
                                                       colsum, colsumsq, (void*)h1b);
    k_bn_finalize<<<1, 512, 0, stream>>>(colsum, colsumsq, gamma, beta, scale, shift);
    k_gemm<DOUT, 2><<<(MP / 128) * 4, 256, 0, stream>>>(h1b, W2T, b2, scale, shift,
                                                        nullptr, nullptr, (void*)outp);
}

// Round 7
// 411.737 us; speedup vs baseline: 7.3147x; 1.0135x over previous
//
#include <hip/hip_runtime.h>

#define NNODES 50000
#define NEDGES 800000
#define DIN    256
#define DOUT   512
#define MP     50048          // ceil(NNODES/128)*128
#define BN_EPS 1e-5f
#define NBLK   196            // ceil(NNODES/256) scan blocks

// k_prep grid segmentation
#define CVT_B  6250           // NNODES*DIN/8/256
#define ZERO_B 391            // 2*MP / 256
#define T1_B   128            // (DOUT/32)*(DIN/32)
#define T2_B   256            // (DOUT/32)*(DOUT/32)
#define PREP_B (CVT_B + ZERO_B + T1_B + T2_B)

typedef __attribute__((ext_vector_type(8))) __bf16 bf16x8;
typedef __attribute__((ext_vector_type(4))) float  floatx4;

// f32 pair -> packed bf16 (compiler emits v_cvt_pk_bf16_f32)
__device__ __forceinline__ uint pkbf(float a, float b) {
    union { __bf16 h[2]; uint u; } cv;
    cv.h[0] = (__bf16)a; cv.h[1] = (__bf16)b;
    return cv.u;
}
__device__ __forceinline__ ushort f2bf(float f) {
    union { __bf16 h; ushort u; } cv;
    cv.h = (__bf16)f;
    return cv.u;
}
__device__ __forceinline__ float bf2f(ushort b) {
    union { uint u; float f; } v; v.u = ((uint)b) << 16;
    return v.f;
}
// BN+ReLU on a packed pair of bf16 while staging
__device__ __forceinline__ uint bnpack(uint u, float s0, float s1, float h0, float h1) {
    float a = fmaxf(bf2f((ushort)(u & 0xffff)) * s0 + h0, 0.f);
    float b = fmaxf(bf2f((ushort)(u >> 16))    * s1 + h1, 0.f);
    return pkbf(a, b);
}
// async global -> LDS, 16B per lane. lds dest must be wave-uniform base (+lane*16 by HW)
__device__ __forceinline__ void gload16(const ushort* g, ushort* l) {
    __builtin_amdgcn_global_load_lds(
        (const __attribute__((address_space(1))) uint*)g,
        (__attribute__((address_space(3))) uint*)l, 16, 0, 0);
}

// ---------------- fused prep: x->bf16 | zero deg/cursor/stats | W1^T | W2^T ----------------
__global__ __launch_bounds__(256) void k_prep(const float* __restrict__ x, ushort* __restrict__ xb,
                                              const float* __restrict__ W1, ushort* __restrict__ W1T,
                                              const float* __restrict__ W2, ushort* __restrict__ W2T,
                                              int* __restrict__ zi, float* __restrict__ zf) {
    __shared__ float tile[32][33];
    int b = blockIdx.x;
    int t = threadIdx.x;
    if (b < CVT_B) {                              // x (f32) -> xb (bf16), 8 elems/thread
        size_t base = ((size_t)b * 256 + t) * 8;
        float4 v0 = *(const float4*)(x + base);
        float4 v1 = *(const float4*)(x + base + 4);
        uint4 o;
        o.x = pkbf(v0.x, v0.y);
        o.y = pkbf(v0.z, v0.w);
        o.z = pkbf(v1.x, v1.y);
        o.w = pkbf(v1.z, v1.w);
        *(uint4*)(xb + base) = o;
        return;
    }
    b -= CVT_B;
    if (b < ZERO_B) {                             // zero deg+cursor (2*MP) and colsum/colsumsq (1024)
        int i = b * 256 + t;
        if (i < 2 * MP) zi[i] = 0;
        if (i < 1024)   zf[i] = 0.f;
        return;
    }
    b -= ZERO_B;
    const float* W; ushort* WT; int K, Nc, bx, by;
    if (b < T1_B) { W = W1; WT = W1T; K = DIN;  Nc = DOUT; bx = b & 15; by = b >> 4; }
    else { b -= T1_B; W = W2; WT = W2T; K = DOUT; Nc = DOUT; bx = b & 15; by = b >> 4; }
    int lx = t & 31, ly = t >> 5;
    #pragma unroll
    for (int p = 0; p < 4; ++p)
        tile[ly + p * 8][lx] = W[(size_t)(by * 32 + ly + p * 8) * Nc + bx * 32 + lx];
    __syncthreads();
    #pragma unroll
    for (int p = 0; p < 4; ++p)
        WT[(size_t)(bx * 32 + ly + p * 8) * K + by * 32 + lx] = f2bf(tile[lx][ly + p * 8]);
}

// ---------------- CSR build ----------------
__global__ void k_count(const int* __restrict__ ei, int* __restrict__ deg) {
    int e = blockIdx.x * 256 + threadIdx.x;
    atomicAdd(&deg[ei[e]], 1);
}

__global__ void k_scan_block(const int* __restrict__ deg, int* __restrict__ rowstart,
                             int* __restrict__ bsum) {
    __shared__ int s[256];
    int t = threadIdx.x;
    int i = blockIdx.x * 256 + t;
    int v = (i < NNODES) ? deg[i] : 0;
    s[t] = v; __syncthreads();
    #pragma unroll
    for (int d = 1; d < 256; d <<= 1) {
        int add = (t >= d) ? s[t - d] : 0;
        __syncthreads();
        s[t] += add;
        __syncthreads();
    }
    if (i < MP) rowstart[i] = s[t] - v;          // exclusive, block-local
    if (t == 255) bsum[blockIdx.x] = s[255];
}

__global__ void k_scan_bsum(const int* __restrict__ bsum, int* __restrict__ bofs) {
    __shared__ int s[256];
    int t = threadIdx.x;
    int v = (t < NBLK) ? bsum[t] : 0;
    s[t] = v; __syncthreads();
    #pragma unroll
    for (int d = 1; d < 256; d <<= 1) {
        int add = (t >= d) ? s[t - d] : 0;
        __syncthreads();
        s[t] += add;
        __syncthreads();
    }
    bofs[t] = s[t] - v;
}

__global__ void k_bucket(const int* __restrict__ ei, const float* __restrict__ ew,
                         const int* __restrict__ rowstart, const int* __restrict__ bofs,
                         int* __restrict__ cursor, int2* __restrict__ cw) {
    int e = blockIdx.x * 256 + threadIdx.x;
    int r = ei[e];
    int c = ei[NEDGES + e];
    float w = ew[e];
    int pos = rowstart[r] + bofs[r >> 8] + atomicAdd(&cursor[r], 1);
    cw[pos] = make_int2(c, __float_as_int(w));
}

// ---------------- gather-aggregate from bf16 x: h0b[n] = bf16( x[n] + sum w_e * x[col_e] ) ----------------
__global__ __launch_bounds__(256) void k_aggregate(const ushort* __restrict__ xb,
                                                   const int2* __restrict__ cw,
                                                   const int* __restrict__ rowstart,
                                                   const int* __restrict__ bofs,
                                                   const int* __restrict__ deg,
                                                   ushort* __restrict__ h0b) {
    int t = threadIdx.x;
    int wv = t >> 6, lane = t & 63;
    int n = blockIdx.x * 4 + wv;
    if (n >= MP) return;
    ushort* dst = h0b + (size_t)n * DIN + lane * 4;
    if (n >= NNODES) {                           // zero the pad rows
        *(ushort4*)dst = make_ushort4(0, 0, 0, 0);
        return;
    }
    const ushort* xl = xb + lane * 4;
    ushort4 sd = *(const ushort4*)(xl + (size_t)n * DIN);
    float4 acc = make_float4(bf2f(sd.x), bf2f(sd.y), bf2f(sd.z), bf2f(sd.w));
    int start = rowstart[n] + bofs[n >> 8];
    int end   = start + deg[n];
    int j = start;
    for (; j + 3 < end; j += 4) {
        int2 e0 = cw[j], e1 = cw[j + 1], e2 = cw[j + 2], e3 = cw[j + 3];
        ushort4 v0 = *(const ushort4*)(xl + (size_t)e0.x * DIN);
        ushort4 v1 = *(const ushort4*)(xl + (size_t)e1.x * DIN);
        ushort4 v2 = *(const ushort4*)(xl + (size_t)e2.x * DIN);
        ushort4 v3 = *(const ushort4*)(xl + (size_t)e3.x * DIN);
        float w0 = __int_as_float(e0.y), w1 = __int_as_float(e1.y);
        float w2 = __int_as_float(e2.y), w3 = __int_as_float(e3.y);
        acc.x += w0 * bf2f(v0.x); acc.y += w0 * bf2f(v0.y); acc.z += w0 * bf2f(v0.z); acc.w += w0 * bf2f(v0.w);
        acc.x += w1 * bf2f(v1.x); acc.y += w1 * bf2f(v1.y); acc.z += w1 * bf2f(v1.z); acc.w += w1 * bf2f(v1.w);
        acc.x += w2 * bf2f(v2.x); acc.y += w2 * bf2f(v2.y); acc.z += w2 * bf2f(v2.z); acc.w += w2 * bf2f(v2.w);
        acc.x += w3 * bf2f(v3.x); acc.y += w3 * bf2f(v3.y); acc.z += w3 * bf2f(v3.z); acc.w += w3 * bf2f(v3.w);
    }
    for (; j < end; ++j) {
        int2 cv = cw[j];
        float w = __int_as_float(cv.y);
        ushort4 v = *(const ushort4*)(xl + (size_t)cv.x * DIN);
        acc.x += w * bf2f(v.x); acc.y += w * bf2f(v.y); acc.z += w * bf2f(v.z); acc.w += w * bf2f(v.w);
    }
    uint2 o;
    o.x = pkbf(acc.x, acc.y);
    o.y = pkbf(acc.z, acc.w);
    *(uint2*)dst = o;
}

// ---------------- bf16 MFMA GEMM: C = A @ BT^T + bias ----------------
// MODE 1: A,B staged via global_load_lds into linear LDS with granule-XOR swizzle;
//         bf16 out (all MP rows) + fused BN-stats column reduction into gsum/gsq.
// MODE 2: B via global_load_lds (swizzled); A reg-staged with BN(scale,shift)+ReLU
//         into padded LDS; f32 out, row<NNODES guard.
template<int KDIM, int MODE>
__global__ __launch_bounds__(256) void k_gemm(const ushort* __restrict__ A,
                                              const ushort* __restrict__ BT,
                                              const float* __restrict__ bias,
                                              const float* __restrict__ scale,
                                              const float* __restrict__ shift,
                                              float* __restrict__ gsum,
                                              float* __restrict__ gsq,
                                              void* __restrict__ out) {
    constexpr int ALD = (MODE == 1) ? 64 : 72;   // MODE1: linear (gload_lds); MODE2: +8 pad
    __shared__ ushort As[128][ALD];
    __shared__ ushort Bs[128][64];               // linear, granule-XOR swizzled

    int t = threadIdx.x;

    // bijective XCD-aware remap (nwg=1564, not %8): each XCD owns a contiguous
    // run of wgid -> the 4 bn-blocks of each bm share the A-panel in one L2
    int nwg  = gridDim.x;
    int q    = nwg >> 3, r = nwg & 7;
    int xcd  = blockIdx.x & 7, loc = blockIdx.x >> 3;
    int wgid = (xcd < r ? xcd * (q + 1) : r * (q + 1) + (xcd - r) * q) + loc;
    int bm   = wgid >> 2;
    int bn   = wgid & 3;

    int lane = t & 63;
    int wv   = t >> 6;
    int wr   = wv >> 1, wc = wv & 1;             // 2x2 waves -> 64x64 each
    int l15  = lane & 15, l4 = lane >> 4;

    int rr = lane >> 3;                          // dest row within 8-row group (0..7)
    int gs = (lane & 7) ^ rr;                    // inverse-swizzled source granule

    int arow = t >> 3;                           // 0..31 (MODE2 A reg-staging)
    int acol = (t & 7) * 8;                      // 0..56

    floatx4 acc[4][4] = {};
    const size_t abase = (size_t)(bm * 128) * KDIM;
    const size_t bbase = (size_t)(bn * 128) * KDIM;

    for (int k0 = 0; k0 < KDIM; k0 += 64) {
        // B: async gload_lds, LDS[r][g] = B[r][g ^ (r&7)]  (granule = 16B)
        #pragma unroll
        for (int p = 0; p < 4; ++p) {
            int r0 = p * 32 + wv * 8;
            gload16(BT + bbase + (size_t)(r0 + rr) * KDIM + k0 + gs * 8, &Bs[r0][0]);
        }
        if (MODE == 1) {
            #pragma unroll
            for (int p = 0; p < 4; ++p) {
                int r0 = p * 32 + wv * 8;
                gload16(A + abase + (size_t)(r0 + rr) * KDIM + k0 + gs * 8, &As[r0][0]);
            }
        } else {
            float4 sc0 = *(const float4*)(scale + k0 + acol);
            float4 sc1 = *(const float4*)(scale + k0 + acol + 4);
            float4 sh0 = *(const float4*)(shift + k0 + acol);
            float4 sh1 = *(const float4*)(shift + k0 + acol + 4);
            #pragma unroll
            for (int p = 0; p < 4; ++p) {
                int row = p * 32 + arow;
                uint4 va = *(const uint4*)(A + abase + (size_t)row * KDIM + k0 + acol);
                va.x = bnpack(va.x, sc0.x, sc0.y, sh0.x, sh0.y);
                va.y = bnpack(va.y, sc0.z, sc0.w, sh0.z, sh0.w);
                va.z = bnpack(va.z, sc1.x, sc1.y, sh1.x, sh1.y);
                va.w = bnpack(va.w, sc1.z, sc1.w, sh1.z, sh1.w);
                *(uint4*)&As[row][acol] = va;
            }
        }
        __syncthreads();                         // drains vmcnt (gload) + lgkm (ds_write)
        #pragma unroll
        for (int ks = 0; ks < 2; ++ks) {
            bf16x8 af[4], bfr[4];
            #pragma unroll
            for (int m = 0; m < 4; ++m) {
                int ar = wr * 64 + m * 16 + l15;
                if (MODE == 1)
                    af[m] = *(const bf16x8*)&As[ar][((ks * 4 + l4) ^ (ar & 7)) * 8];
                else
                    af[m] = *(const bf16x8*)&As[ar][ks * 32 + l4 * 8];
            }
            #pragma unroll
            for (int n = 0; n < 4; ++n) {
                int br = wc * 64 + n * 16 + l15;
                bfr[n] = *(const bf16x8*)&Bs[br][((ks * 4 + l4) ^ (br & 7)) * 8];
            }
            #pragma unroll
            for (int m = 0; m < 4; ++m)
                #pragma unroll
                for (int n = 0; n < 4; ++n)
                    acc[m][n] = __builtin_amdgcn_mfma_f32_16x16x32_bf16(af[m], bfr[n], acc[m][n], 0, 0, 0);
        }
        __syncthreads();
    }

    // epilogue: D row = (lane>>4)*4 + reg, col = lane&15   [m89-verified layout]
    float csum[4], csq[4];
    #pragma unroll
    for (int n = 0; n < 4; ++n) { csum[n] = 0.f; csq[n] = 0.f; }

    #pragma unroll
    for (int n = 0; n < 4; ++n) {
        int col = bn * 128 + wc * 64 + n * 16 + l15;
        float bv = bias[col];
        #pragma unroll
        for (int m = 0; m < 4; ++m) {
            int rbase = bm * 128 + wr * 64 + m * 16 + l4 * 4;
            #pragma unroll
            for (int i = 0; i < 4; ++i) {
                int grow = rbase + i;
                float vv = acc[m][n][i] + bv;
                if (MODE == 1) {
                    ((ushort*)out)[(size_t)grow * DOUT + col] = f2bf(vv);
                    if (grow < NNODES) { csum[n] += vv; csq[n] += vv * vv; }
                } else {
                    if (grow < NNODES)
                        ((float*)out)[(size_t)grow * DOUT + col] = vv;
                }
            }
        }
    }

    if (MODE == 1) {
        // per-block column reduce in LDS (reuse As: 8KB of 16KB), then 2 atomics/column
        float* sumarr = (float*)&As[0][0];       // 8 x 128
        float* sqarr  = sumarr + 1024;           // 8 x 128
        int cid = wr * 4 + l4;                   // 0..7, unique (cid,colL) writer
        #pragma unroll
        for (int n = 0; n < 4; ++n) {
            int colL = wc * 64 + n * 16 + l15;
            sumarr[cid * 128 + colL] = csum[n];
            sqarr [cid * 128 + colL] = csq[n];
        }
        __syncthreads();
        if (t < 128) {
            float s = 0.f, q2 = 0.f;
            #pragma unroll
            for (int k = 0; k < 8; ++k) { s += sumarr[k * 128 + t]; q2 += sqarr[k * 128 + t]; }
            atomicAdd(&gsum[bn * 128 + t], s);
            atomicAdd(&gsq [bn * 128 + t], q2);
        }
    }
}

__global__ void k_bn_finalize(const float* __restrict__ sum, const float* __restrict__ sumsq,
                              const float* __restrict__ gamma, const float* __restrict__ beta,
                              float* __restrict__ scale, float* __restrict__ shift) {
    int c = threadIdx.x;                         // 512 threads
    float mean = sum[c] * (1.0f / NNODES);
    float var  = sumsq[c] * (1.0f / NNODES) - mean * mean;
    float sc   = gamma[c] * rsqrtf(var + BN_EPS);
    scale[c] = sc;
    shift[c] = beta[c] - mean * sc;
}

extern "C" void kernel_launch(void* const* d_in, const int* in_sizes, int n_in,
                              void* d_out, int out_size, void* d_ws, size_t ws_size,
                              hipStream_t stream) {
    const float* x     = (const float*)d_in[0];
    const int*   ei    = (const int*)  d_in[1];
    const float* ew    = (const float*)d_in[2];
    const float* W1    = (const float*)d_in[3];
    const float* b1    = (const float*)d_in[4];
    const float* gamma = (const float*)d_in[5];
    const float* beta  = (const float*)d_in[6];
    const float* W2    = (const float*)d_in[7];
    const float* b2    = (const float*)d_in[8];

    // ---- ws layout (~52 MB) ----
    char* ws = (char*)d_ws;
    ushort* h1b = (ushort*)ws;                       size_t off = (size_t)MP * DOUT * 2;
    ushort* W1T = (ushort*)(ws + off);               off += (size_t)DOUT * DIN * 2;
    ushort* W2T = (ushort*)(ws + off);               off += (size_t)DOUT * DOUT * 2;
    float* colsum   = (float*)(ws + off);            off += 512 * 4;   // colsum+colsumsq contiguous (1024 f32)
    float* colsumsq = (float*)(ws + off);            off += 512 * 4;
    float* scale    = (float*)(ws + off);            off += 512 * 4;
    float* shift    = (float*)(ws + off);            off += 512 * 4;

    // ---- d_out double-duty: h0b + xb + CSR scratch, all dead before GEMM2 writes ----
    char* ob = (char*)d_out;
    ushort* h0b     = (ushort*)ob;                   size_t ooff = (size_t)MP * DIN * 2;
    ushort* xb      = (ushort*)(ob + ooff);          ooff += (size_t)NNODES * DIN * 2;
    int2*   cw      = (int2*)(ob + ooff);            ooff += (size_t)NEDGES * 8;
    int*    deg     = (int*)(ob + ooff);             ooff += (size_t)MP * 4;   // deg+cursor adjacent for zeroing
    int*    cursor  = (int*)(ob + ooff);             ooff += (size_t)MP * 4;
    int*    rowstart= (int*)(ob + ooff);             ooff += (size_t)MP * 4;
    int*    bsum    = (int*)(ob + ooff);             ooff += 256 * 4;
    int*    bofs    = (int*)(ob + ooff);             ooff += 256 * 4;
    float*  outp    = (float*)d_out;

    // fused prep: x->bf16, zero deg/cursor/stats, transpose W1/W2 to bf16
    k_prep<<<PREP_B, 256, 0, stream>>>(x, xb, W1, W1T, W2, W2T, deg, colsum);

    // CSR build
    k_count<<<NEDGES / 256, 256, 0, stream>>>(ei, deg);
    k_scan_block<<<NBLK, 256, 0, stream>>>(deg, rowstart, bsum);
    k_scan_bsum<<<1, 256, 0, stream>>>(bsum, bofs);
    k_bucket<<<NEDGES / 256, 256, 0, stream>>>(ei, ew, rowstart, bofs, cursor, cw);

    // aggregate (bf16 gather, no atomics) -> bf16
    k_aggregate<<<MP / 4, 256, 0, stream>>>(xb, cw, rowstart, bofs, deg, h0b);

    // MLP: GEMM1 (+stats) -> tiny finalize -> GEMM2 (BN/ReLU fused into A-staging)
    k_gemm<DIN, 1><<<(MP / 128) * 4, 256, 0, stream>>>(h0b, W1T, b1, nullptr, nullptr,
                                                       colsum, colsumsq, (void*)h1b);
    k_bn_finalize<<<1, 512, 0, stream>>>(colsum, colsumsq, gamma, beta, scale, shift);
    k_gemm<DOUT, 2><<<(MP / 128) * 4, 256, 0, stream>>>(h1b, W2T, b2, scale, shift,
                                                        nullptr, nullptr, (void*)outp);
}